// Round 2
// baseline (1950.642 us; speedup 1.0000x reference)
//
#include <hip/hip_runtime.h>
#include <hip/hip_bf16.h>

typedef __hip_bfloat16 bf16;
typedef unsigned short ushort_t;

__device__ __forceinline__ float us2f(unsigned short u) {
    unsigned int x = ((unsigned int)u) << 16;
    return __uint_as_float(x);
}

// ---------------------------------------------------------------------------
// Elementwise add: q = src + pos (fp32)
// ---------------------------------------------------------------------------
__global__ __launch_bounds__(256) void add_f32_kernel(
    const float* __restrict__ a, const float* __restrict__ b,
    float* __restrict__ o, int n)
{
    int i = blockIdx.x * 256 + threadIdx.x;
    if (i < n) o[i] = a[i] + b[i];
}

// ---------------------------------------------------------------------------
// Tiled GEMM: out[M,N] = A[M,K] @ W[K,N] + bias[N] (+ resid[M,N]) (relu?)
// A is fp32 or bf16 (A_BF16); W/bias/resid fp32; out fp32 or bf16 (OUT_BF16).
// 64x64 tile, 256 threads, 4x4 microtile, K-step 16.
// ---------------------------------------------------------------------------
template<bool RELU, bool OUT_BF16, bool HAS_RESID, bool A_BF16>
__global__ __launch_bounds__(256) void gemm_tiled(
    const void* __restrict__ Av, const float* __restrict__ W,
    const float* __restrict__ bias, const float* __restrict__ resid,
    void* __restrict__ outv, int M, int N, int K)
{
    __shared__ float As[16][65];
    __shared__ float Bs[16][65];
    const int tid = threadIdx.x;
    const int m0 = blockIdx.y * 64;
    const int n0 = blockIdx.x * 64;
    const int ar = tid >> 2;           // 0..63 : A row in tile
    const int ac = (tid & 3) << 2;     // 0,4,8,12 : A col (k) in tile
    const int wr = tid >> 4;           // 0..15 : W row (k) in tile
    const int wc = (tid & 15) << 2;    // 0..60 : W col in tile
    const int rowb = (tid >> 4) << 2;  // 0..60 : output row base
    const int colb = (tid & 15) << 2;  // output col base

    float acc[4][4] = {};

    for (int k0 = 0; k0 < K; k0 += 16) {
        // ---- stage A tile (transposed into As[k][m]) ----
        {
            float a0 = 0.f, a1 = 0.f, a2 = 0.f, a3 = 0.f;
            int m = m0 + ar;
            if (m < M) {
                if (A_BF16) {
                    const ushort4 u = *reinterpret_cast<const ushort4*>(
                        (const ushort_t*)Av + (size_t)m * K + k0 + ac);
                    a0 = us2f(u.x); a1 = us2f(u.y); a2 = us2f(u.z); a3 = us2f(u.w);
                } else {
                    const float4 f = *reinterpret_cast<const float4*>(
                        (const float*)Av + (size_t)m * K + k0 + ac);
                    a0 = f.x; a1 = f.y; a2 = f.z; a3 = f.w;
                }
            }
            As[ac + 0][ar] = a0;
            As[ac + 1][ar] = a1;
            As[ac + 2][ar] = a2;
            As[ac + 3][ar] = a3;
        }
        // ---- stage W tile ----
        {
            float w0 = 0.f, w1 = 0.f, w2 = 0.f, w3 = 0.f;
            const float* p = W + (size_t)(k0 + wr) * N + n0 + wc;
            if (n0 + wc + 3 < N) {
                const float4 f = *reinterpret_cast<const float4*>(p);
                w0 = f.x; w1 = f.y; w2 = f.z; w3 = f.w;
            } else {
                if (n0 + wc + 0 < N) w0 = p[0];
                if (n0 + wc + 1 < N) w1 = p[1];
                if (n0 + wc + 2 < N) w2 = p[2];
                if (n0 + wc + 3 < N) w3 = p[3];
            }
            Bs[wr][wc + 0] = w0;
            Bs[wr][wc + 1] = w1;
            Bs[wr][wc + 2] = w2;
            Bs[wr][wc + 3] = w3;
        }
        __syncthreads();
        #pragma unroll
        for (int kk = 0; kk < 16; ++kk) {
            float av[4], wv[4];
            #pragma unroll
            for (int i = 0; i < 4; ++i) av[i] = As[kk][rowb + i];
            #pragma unroll
            for (int j = 0; j < 4; ++j) wv[j] = Bs[kk][colb + j];
            #pragma unroll
            for (int i = 0; i < 4; ++i)
                #pragma unroll
                for (int j = 0; j < 4; ++j)
                    acc[i][j] = fmaf(av[i], wv[j], acc[i][j]);
        }
        __syncthreads();
    }

    // ---- epilogue ----
    #pragma unroll
    for (int i = 0; i < 4; ++i) {
        int m = m0 + rowb + i;
        if (m >= M) continue;
        #pragma unroll
        for (int j = 0; j < 4; ++j) {
            int n = n0 + colb + j;
            if (n >= N) continue;
            float v = acc[i][j] + bias[n];
            if (HAS_RESID) v += resid[(size_t)m * N + n];
            if (RELU) v = fmaxf(v, 0.f);
            if (OUT_BF16)
                ((bf16*)outv)[(size_t)m * N + n] = __float2bfloat16(v);
            else
                ((float*)outv)[(size_t)m * N + n] = v;
        }
    }
}

// ---------------------------------------------------------------------------
// MS-deformable attention sampling.
// One block (256 threads) per (b, q). thread = h*32 + d.
// Includes per-head softmax over the 20 logits.
// ---------------------------------------------------------------------------
__global__ __launch_bounds__(256) void msda_kernel(
    const float* __restrict__ offs,     // [M,320]
    const float* __restrict__ logits,   // [M,160]
    const float* __restrict__ refp,     // [B,L,5,2]
    const float* __restrict__ value,    // [M,256] = (B,L,H,DH)
    float* __restrict__ out,            // [M,256]
    int L)
{
    const int bq = blockIdx.x;
    const int b = bq / L;
    const int tid = threadIdx.x;
    const int h = tid >> 5;
    const int d = tid & 31;
    (void)d;

    __shared__ float s_off[320];
    __shared__ float s_attn[160];
    __shared__ float s_ref[10];

    for (int i = tid; i < 320; i += 256) s_off[i] = offs[(size_t)bq * 320 + i];
    for (int i = tid; i < 160; i += 256) s_attn[i] = logits[(size_t)bq * 160 + i];
    if (tid < 10) s_ref[tid] = refp[(size_t)bq * 10 + tid];
    __syncthreads();

    // per-head softmax over 20 elements, one leader thread per head
    if ((tid & 31) == 0) {
        float mx = -1e30f;
        #pragma unroll
        for (int i = 0; i < 20; ++i) mx = fmaxf(mx, s_attn[h * 20 + i]);
        float ssum = 0.f;
        #pragma unroll
        for (int i = 0; i < 20; ++i) {
            float e = __expf(s_attn[h * 20 + i] - mx);
            s_attn[h * 20 + i] = e;
            ssum += e;
        }
        float inv = 1.f / ssum;
        #pragma unroll
        for (int i = 0; i < 20; ++i) s_attn[h * 20 + i] *= inv;
    }
    __syncthreads();

    const int Hs[5] = {100, 50, 25, 13, 7};
    const int Ws[5] = {100, 50, 25, 13, 7};
    const int st[5] = {0, 10000, 12500, 13125, 13294};

    const size_t vbase = (size_t)b * L * 256 + tid;  // + (s+idx)*256

    float acc = 0.f;
    #pragma unroll
    for (int l = 0; l < 5; ++l) {
        const float rx = s_ref[l * 2 + 0];
        const float ry = s_ref[l * 2 + 1];
        const float Wf = (float)Ws[l];
        const float Hf = (float)Hs[l];
        const int Wi = Ws[l], Hi = Hs[l], s0 = st[l];
        #pragma unroll
        for (int p = 0; p < 4; ++p) {
            const float ox = s_off[h * 40 + l * 8 + p * 2 + 0];
            const float oy = s_off[h * 40 + l * 8 + p * 2 + 1];
            const float px = (rx + ox / Wf) * Wf - 0.5f;
            const float py = (ry + oy / Hf) * Hf - 0.5f;
            const float x0 = floorf(px);
            const float y0 = floorf(py);
            const float lx = px - x0;
            const float ly = py - y0;
            const int x0i = (int)x0;
            const int y0i = (int)y0;
            const float a = s_attn[h * 20 + l * 4 + p];

            float samp = 0.f;
            #pragma unroll
            for (int dy = 0; dy < 2; ++dy) {
                #pragma unroll
                for (int dx = 0; dx < 2; ++dx) {
                    const int xi = x0i + dx;
                    const int yi = y0i + dy;
                    const bool valid = (xi >= 0) && (xi < Wi) && (yi >= 0) && (yi < Hi);
                    const float wx = dx ? lx : (1.f - lx);
                    const float wy = dy ? ly : (1.f - ly);
                    if (valid) {
                        const int idx = yi * Wi + xi;
                        const float g = value[vbase + (size_t)(s0 + idx) * 256];
                        samp += wx * wy * g;
                    }
                }
            }
            acc += a * samp;
        }
    }
    out[(size_t)bq * 256 + tid] = acc;
}

// ---------------------------------------------------------------------------
// LayerNorm over last dim (256). One block (256 threads) per row. fp32->fp32.
// ---------------------------------------------------------------------------
__global__ __launch_bounds__(256) void ln_kernel(
    const float* __restrict__ y, const float* __restrict__ g,
    const float* __restrict__ bta, float* __restrict__ out)
{
    const int row = blockIdx.x;
    const int tid = threadIdx.x;
    float v = y[(size_t)row * 256 + tid];
    float s = v, ss = v * v;
    #pragma unroll
    for (int o = 32; o > 0; o >>= 1) {
        s += __shfl_down(s, o);
        ss += __shfl_down(ss, o);
    }
    __shared__ float red[8];
    const int wid = tid >> 6, lane = tid & 63;
    if (lane == 0) { red[wid] = s; red[4 + wid] = ss; }
    __syncthreads();
    const float S = red[0] + red[1] + red[2] + red[3];
    const float SS = red[4] + red[5] + red[6] + red[7];
    const float mean = S * (1.f / 256.f);
    const float var = SS * (1.f / 256.f) - mean * mean;
    const float rs = rsqrtf(var + 1e-5f);
    out[(size_t)row * 256 + tid] = (v - mean) * rs * g[tid] + bta[tid];
}

// ---------------------------------------------------------------------------
extern "C" void kernel_launch(void* const* d_in, const int* in_sizes, int n_in,
                              void* d_out, int out_size, void* d_ws, size_t ws_size,
                              hipStream_t stream)
{
    const int B = 2, L = 13343, C = 256, FF = 2048;
    const int M = B * L;  // 26686

    const float* src  = (const float*)d_in[0];
    const float* pos  = (const float*)d_in[1];
    const float* refp = (const float*)d_in[2];
    const float* wv   = (const float*)d_in[3];
    const float* bv   = (const float*)d_in[4];
    const float* wo   = (const float*)d_in[5];
    const float* bo   = (const float*)d_in[6];
    const float* wa   = (const float*)d_in[7];
    const float* ba   = (const float*)d_in[8];
    const float* wout = (const float*)d_in[9];
    const float* bout = (const float*)d_in[10];
    const float* ln1g = (const float*)d_in[11];
    const float* ln1b = (const float*)d_in[12];
    const float* w1   = (const float*)d_in[13];
    const float* b1   = (const float*)d_in[14];
    const float* w2   = (const float*)d_in[15];
    const float* b2   = (const float*)d_in[16];
    const float* ln2g = (const float*)d_in[17];
    const float* ln2b = (const float*)d_in[18];

    char* ws = (char*)d_ws;
    const size_t MB = 1ull << 20;
    // Layout (phase 1):  x lives at 0 into phase 2; temporaries above it.
    float* x      = (float*)(ws + 0);          // M*256 f32 = 27.3 MB
    float* q      = (float*)(ws + 28 * MB);    // 27.3 MB
    float* value  = (float*)(ws + 56 * MB);    // 27.3 MB
    float* offs   = (float*)(ws + 84 * MB);    // M*320 f32 = 34.2 MB
    float* logits = (float*)(ws + 120 * MB);   // M*160 f32 = 17.1 MB
    float* accb   = (float*)(ws + 140 * MB);   // 27.3 MB
    float* y      = (float*)(ws + 168 * MB);   // 27.3 MB (peak: 196 MB)
    // Phase 2 overlays dead phase-1 temporaries:
    bf16*  hbuf   = (bf16*)(ws + 28 * MB);     // M*2048 bf16 = 109.3 MB -> ends 137.3
    float* z      = (float*)(ws + 140 * MB);   // 27.3 MB
    (void)ws_size; (void)n_in; (void)in_sizes; (void)out_size;

    const int mt = (M + 63) / 64;  // 417

    // q = src + pos
    add_f32_kernel<<<(M * C + 255) / 256, 256, 0, stream>>>(src, pos, q, M * C);

    // value = src @ wv + bv
    gemm_tiled<false, false, false, false><<<dim3(4, mt), 256, 0, stream>>>(
        src, wv, bv, nullptr, value, M, 256, 256);

    // offs = q @ wo + bo
    gemm_tiled<false, false, false, false><<<dim3(5, mt), 256, 0, stream>>>(
        q, wo, bo, nullptr, offs, M, 320, 256);

    // logits = q @ wa + ba
    gemm_tiled<false, false, false, false><<<dim3(3, mt), 256, 0, stream>>>(
        q, wa, ba, nullptr, logits, M, 160, 256);

    // deformable attention sampling -> accb
    msda_kernel<<<M, 256, 0, stream>>>(offs, logits, refp, value, accb, L);

    // y = accb @ wout + bout + src
    gemm_tiled<false, false, true, false><<<dim3(4, mt), 256, 0, stream>>>(
        accb, wout, bout, src, y, M, 256, 256);

    // x = LN(y)
    ln_kernel<<<M, 256, 0, stream>>>(y, ln1g, ln1b, x);

    // h = relu(x @ w1 + b1)  (bf16 out to halve workspace/traffic)
    gemm_tiled<true, true, false, false><<<dim3(32, mt), 256, 0, stream>>>(
        x, w1, b1, nullptr, hbuf, M, FF, 256);

    // z = h @ w2 + b2 + x
    gemm_tiled<false, false, true, true><<<dim3(4, mt), 256, 0, stream>>>(
        hbuf, w2, b2, x, z, M, 256, FF);

    // out = LN(z)
    ln_kernel<<<M, 256, 0, stream>>>(z, ln2g, ln2b, (float*)d_out);
}

// Round 3
// 832.050 us; speedup vs baseline: 2.3444x; 2.3444x over previous
//
#include <hip/hip_runtime.h>
#include <hip/hip_bf16.h>

typedef __hip_bfloat16 bf16;
typedef unsigned short ushort_t;
typedef __attribute__((ext_vector_type(8))) short bf16x8;
typedef __attribute__((ext_vector_type(4))) float f32x4;

__device__ __forceinline__ float us2f(unsigned short u) {
    unsigned int x = ((unsigned int)u) << 16;
    return __uint_as_float(x);
}

// ---------------------------------------------------------------------------
// q_b = bf16(a + b)
// ---------------------------------------------------------------------------
__global__ __launch_bounds__(256) void add_cast_kernel(
    const float* __restrict__ a, const float* __restrict__ b,
    bf16* __restrict__ o, int n)
{
    int i = blockIdx.x * 256 + threadIdx.x;
    if (i < n) o[i] = __float2bfloat16(a[i] + b[i]);
}

// ---------------------------------------------------------------------------
// o = bf16(a)
// ---------------------------------------------------------------------------
__global__ __launch_bounds__(256) void cast_kernel(
    const float* __restrict__ a, bf16* __restrict__ o, int n)
{
    int i = blockIdx.x * 256 + threadIdx.x;
    if (i < n) o[i] = __float2bfloat16(a[i]);
}

// ---------------------------------------------------------------------------
// Wt[n][k] = bf16(W[k][n])   (32x32 LDS tile transpose)
// ---------------------------------------------------------------------------
__global__ __launch_bounds__(256) void transpose_cast_kernel(
    const float* __restrict__ W, bf16* __restrict__ Wt, int K, int N)
{
    __shared__ float tile[32][33];
    const int tx = threadIdx.x & 31, ty = threadIdx.x >> 5;  // 32 x 8
    const int nb = blockIdx.x * 32, kb = blockIdx.y * 32;
    #pragma unroll
    for (int i = 0; i < 32; i += 8) {
        int k = kb + ty + i, n = nb + tx;
        tile[ty + i][tx] = (k < K && n < N) ? W[(size_t)k * N + n] : 0.f;
    }
    __syncthreads();
    #pragma unroll
    for (int i = 0; i < 32; i += 8) {
        int n = nb + ty + i, k = kb + tx;
        if (n < N && k < K)
            Wt[(size_t)n * K + k] = __float2bfloat16(tile[tx][ty + i]);
    }
}

// ---------------------------------------------------------------------------
// MFMA bf16 GEMM: out[M,N] = A[M,K] @ Bt[N,K]^T + bias (+resid) (relu?)
// 128x128 block tile, 4 waves, each wave 64x64 = 4x4 MFMA 16x16x32 tiles.
// LDS row stride 40 bf16 (80 B): 16B-aligned ds_read_b128, 2-way banks (free).
// ---------------------------------------------------------------------------
template<bool RELU, bool OUT_BF16, bool HAS_RESID>
__global__ __launch_bounds__(256) void gemm_mfma(
    const ushort_t* __restrict__ A,    // [M][K] bf16
    const ushort_t* __restrict__ Bt,   // [N][K] bf16
    const float* __restrict__ bias,    // [N] f32
    const float* __restrict__ resid,   // [M][N] f32
    void* __restrict__ outv, int M, int N, int K)
{
    __shared__ ushort_t Asmem[128 * 40];
    __shared__ ushort_t Bsmem[128 * 40];
    const int tid = threadIdx.x;
    const int lane = tid & 63;
    const int wave = tid >> 6;
    const int quad = lane >> 4;
    const int l16 = lane & 15;
    const int wm = wave >> 1, wn = wave & 1;
    const int m0 = blockIdx.y * 128;
    const int n0 = blockIdx.x * 128;

    // staging coords: thread covers rows r0 and r0+64 at k-chunk kg (8 bf16)
    const int r0 = tid >> 2;
    const int kg = (tid & 3) * 8;

    f32x4 acc[4][4] = {};

    for (int k0 = 0; k0 < K; k0 += 32) {
        #pragma unroll
        for (int half = 0; half < 2; ++half) {
            const int r = r0 + half * 64;
            int4 av = {0, 0, 0, 0};
            const int m = m0 + r;
            if (m < M)
                av = *reinterpret_cast<const int4*>(A + (size_t)m * K + k0 + kg);
            *reinterpret_cast<int4*>(&Asmem[r * 40 + kg]) = av;

            int4 bv = {0, 0, 0, 0};
            const int n = n0 + r;
            if (n < N)
                bv = *reinterpret_cast<const int4*>(Bt + (size_t)n * K + k0 + kg);
            *reinterpret_cast<int4*>(&Bsmem[r * 40 + kg]) = bv;
        }
        __syncthreads();

        bf16x8 af[4], bfr[4];
        #pragma unroll
        for (int i = 0; i < 4; ++i) {
            const int row = wm * 64 + i * 16 + l16;
            af[i] = *reinterpret_cast<const bf16x8*>(&Asmem[row * 40 + quad * 8]);
        }
        #pragma unroll
        for (int j = 0; j < 4; ++j) {
            const int row = wn * 64 + j * 16 + l16;
            bfr[j] = *reinterpret_cast<const bf16x8*>(&Bsmem[row * 40 + quad * 8]);
        }
        #pragma unroll
        for (int i = 0; i < 4; ++i)
            #pragma unroll
            for (int j = 0; j < 4; ++j)
                acc[i][j] = __builtin_amdgcn_mfma_f32_16x16x32_bf16(
                    af[i], bfr[j], acc[i][j], 0, 0, 0);
        __syncthreads();
    }

    // epilogue: C/D layout col = lane&15, row = quad*4 + reg  [m89/m91]
    #pragma unroll
    for (int i = 0; i < 4; ++i) {
        const int mbase = m0 + wm * 64 + i * 16 + quad * 4;
        #pragma unroll
        for (int j = 0; j < 4; ++j) {
            const int n = n0 + wn * 64 + j * 16 + l16;
            if (n >= N) continue;
            const float bval = bias[n];
            #pragma unroll
            for (int r = 0; r < 4; ++r) {
                const int m = mbase + r;
                if (m >= M) continue;
                float v = acc[i][j][r] + bval;
                if (HAS_RESID) v += resid[(size_t)m * N + n];
                if (RELU) v = fmaxf(v, 0.f);
                if (OUT_BF16)
                    ((bf16*)outv)[(size_t)m * N + n] = __float2bfloat16(v);
                else
                    ((float*)outv)[(size_t)m * N + n] = v;
            }
        }
    }
}

// ---------------------------------------------------------------------------
// MS-deformable attention sampling. One block per (b,q); thread = h*32 + d.
// value is bf16 now.
// ---------------------------------------------------------------------------
__global__ __launch_bounds__(256) void msda_kernel(
    const float* __restrict__ offs,      // [M,320]
    const float* __restrict__ logits,    // [M,160]
    const float* __restrict__ refp,      // [B,L,5,2]
    const ushort_t* __restrict__ value,  // [M,256] bf16
    bf16* __restrict__ out,              // [M,256] bf16
    int L)
{
    const int bq = blockIdx.x;
    const int b = bq / L;
    const int tid = threadIdx.x;
    const int h = tid >> 5;

    __shared__ float s_off[320];
    __shared__ float s_attn[160];
    __shared__ float s_ref[10];

    for (int i = tid; i < 320; i += 256) s_off[i] = offs[(size_t)bq * 320 + i];
    for (int i = tid; i < 160; i += 256) s_attn[i] = logits[(size_t)bq * 160 + i];
    if (tid < 10) s_ref[tid] = refp[(size_t)bq * 10 + tid];
    __syncthreads();

    if ((tid & 31) == 0) {
        float mx = -1e30f;
        #pragma unroll
        for (int i = 0; i < 20; ++i) mx = fmaxf(mx, s_attn[h * 20 + i]);
        float ssum = 0.f;
        #pragma unroll
        for (int i = 0; i < 20; ++i) {
            float e = __expf(s_attn[h * 20 + i] - mx);
            s_attn[h * 20 + i] = e;
            ssum += e;
        }
        float inv = 1.f / ssum;
        #pragma unroll
        for (int i = 0; i < 20; ++i) s_attn[h * 20 + i] *= inv;
    }
    __syncthreads();

    const int HW[5] = {100, 50, 25, 13, 7};
    const int st[5] = {0, 10000, 12500, 13125, 13294};

    const size_t vbase = (size_t)b * L * 256 + tid;

    float acc = 0.f;
    #pragma unroll
    for (int l = 0; l < 5; ++l) {
        const float rx = s_ref[l * 2 + 0];
        const float ry = s_ref[l * 2 + 1];
        const int Wi = HW[l], Hi = HW[l], s0 = st[l];
        const float Wf = (float)Wi, Hf = (float)Hi;
        #pragma unroll
        for (int p = 0; p < 4; ++p) {
            const float ox = s_off[h * 40 + l * 8 + p * 2 + 0];
            const float oy = s_off[h * 40 + l * 8 + p * 2 + 1];
            const float px = (rx + ox / Wf) * Wf - 0.5f;
            const float py = (ry + oy / Hf) * Hf - 0.5f;
            const float x0 = floorf(px);
            const float y0 = floorf(py);
            const float lx = px - x0;
            const float ly = py - y0;
            const int x0i = (int)x0;
            const int y0i = (int)y0;
            const float a = s_attn[h * 20 + l * 4 + p];

            float samp = 0.f;
            #pragma unroll
            for (int dy = 0; dy < 2; ++dy) {
                #pragma unroll
                for (int dx = 0; dx < 2; ++dx) {
                    const int xi = x0i + dx;
                    const int yi = y0i + dy;
                    const bool valid = (xi >= 0) && (xi < Wi) && (yi >= 0) && (yi < Hi);
                    const float wx = dx ? lx : (1.f - lx);
                    const float wy = dy ? ly : (1.f - ly);
                    if (valid) {
                        const int idx = yi * Wi + xi;
                        samp += wx * wy * us2f(value[vbase + (size_t)(s0 + idx) * 256]);
                    }
                }
            }
            acc += a * samp;
        }
    }
    out[(size_t)bq * 256 + tid] = __float2bfloat16(acc);
}

// ---------------------------------------------------------------------------
// LayerNorm (256). DUAL: also emit bf16 copy.
// ---------------------------------------------------------------------------
template<bool DUAL>
__global__ __launch_bounds__(256) void ln_kernel(
    const float* __restrict__ y, const float* __restrict__ g,
    const float* __restrict__ bta, float* __restrict__ outf,
    bf16* __restrict__ outb)
{
    const int row = blockIdx.x;
    const int tid = threadIdx.x;
    float v = y[(size_t)row * 256 + tid];
    float s = v, ss = v * v;
    #pragma unroll
    for (int o = 32; o > 0; o >>= 1) {
        s += __shfl_down(s, o);
        ss += __shfl_down(ss, o);
    }
    __shared__ float red[8];
    const int wid = tid >> 6, lane = tid & 63;
    if (lane == 0) { red[wid] = s; red[4 + wid] = ss; }
    __syncthreads();
    const float S = red[0] + red[1] + red[2] + red[3];
    const float SS = red[4] + red[5] + red[6] + red[7];
    const float mean = S * (1.f / 256.f);
    const float var = SS * (1.f / 256.f) - mean * mean;
    const float rs = rsqrtf(var + 1e-5f);
    const float o = (v - mean) * rs * g[tid] + bta[tid];
    outf[(size_t)row * 256 + tid] = o;
    if (DUAL) outb[(size_t)row * 256 + tid] = __float2bfloat16(o);
}

// ---------------------------------------------------------------------------
extern "C" void kernel_launch(void* const* d_in, const int* in_sizes, int n_in,
                              void* d_out, int out_size, void* d_ws, size_t ws_size,
                              hipStream_t stream)
{
    const int B = 2, L = 13343, C = 256, FF = 2048;
    const int M = B * L;  // 26686

    const float* src  = (const float*)d_in[0];
    const float* pos  = (const float*)d_in[1];
    const float* refp = (const float*)d_in[2];
    const float* wv   = (const float*)d_in[3];
    const float* bv   = (const float*)d_in[4];
    const float* wo   = (const float*)d_in[5];
    const float* bo   = (const float*)d_in[6];
    const float* wa   = (const float*)d_in[7];
    const float* ba   = (const float*)d_in[8];
    const float* wout = (const float*)d_in[9];
    const float* bout = (const float*)d_in[10];
    const float* ln1g = (const float*)d_in[11];
    const float* ln1b = (const float*)d_in[12];
    const float* w1   = (const float*)d_in[13];
    const float* b1   = (const float*)d_in[14];
    const float* w2   = (const float*)d_in[15];
    const float* b2   = (const float*)d_in[16];
    const float* ln2g = (const float*)d_in[17];
    const float* ln2b = (const float*)d_in[18];

    char* ws = (char*)d_ws;
    const size_t MB = 1ull << 20;
    // ---- workspace overlay (peak ~183 MB) ----
    // early phase (dead before h GEMM):
    bf16*  src_b  = (bf16*)(ws + 0);         // 13.7 MB
    bf16*  q_b    = (bf16*)(ws + 14 * MB);   // 13.7
    bf16*  val_b  = (bf16*)(ws + 28 * MB);   // 13.7
    float* offs   = (float*)(ws + 42 * MB);  // 34.2
    float* logits = (float*)(ws + 77 * MB);  // 17.1 -> ends 94.1
    bf16*  acc_b  = (bf16*)(ws + 95 * MB);   // 13.7 -> ends 108.7
    // h overlays all of the above once they're dead:
    bf16*  h_b    = (bf16*)(ws + 0);         // M*2048 bf16 = 109.3 MB
    float* y      = (float*)(ws + 110 * MB); // 27.3 -> ends 137.3 (dead after LN1)
    float* z      = (float*)(ws + 110 * MB); // overlays y (written after y dead)
    bf16*  x_b    = (bf16*)(ws + 138 * MB);  // 13.7
    float* x_f    = (float*)(ws + 152 * MB); // 27.3 -> ends 179.3
    // bf16-transposed weights:
    bf16* wvt   = (bf16*)(ws + 180 * MB);              // 256*256
    bf16* wot   = wvt + 256 * 256;                     // 320*256
    bf16* wat   = wot + 320 * 256;                     // 160*256
    bf16* woutt = wat + 160 * 256;                     // 256*256
    bf16* w1t   = woutt + 256 * 256;                   // 2048*256
    bf16* w2t   = w1t + 2048 * 256;                    // 256*2048 -> ends ~182.6 MB
    (void)ws_size; (void)n_in; (void)in_sizes; (void)out_size;

    const int mt = (M + 127) / 128;  // 209

    // ---- weight transpose-casts ----
    transpose_cast_kernel<<<dim3(8, 8),   256, 0, stream>>>(wv,   wvt,   256, 256);
    transpose_cast_kernel<<<dim3(10, 8),  256, 0, stream>>>(wo,   wot,   256, 320);
    transpose_cast_kernel<<<dim3(5, 8),   256, 0, stream>>>(wa,   wat,   256, 160);
    transpose_cast_kernel<<<dim3(8, 8),   256, 0, stream>>>(wout, woutt, 256, 256);
    transpose_cast_kernel<<<dim3(64, 8),  256, 0, stream>>>(w1,   w1t,   256, 2048);
    transpose_cast_kernel<<<dim3(8, 64),  256, 0, stream>>>(w2,   w2t,   2048, 256);

    // ---- activation casts ----
    cast_kernel<<<(M * C + 255) / 256, 256, 0, stream>>>(src, src_b, M * C);
    add_cast_kernel<<<(M * C + 255) / 256, 256, 0, stream>>>(src, pos, q_b, M * C);

    // value = src @ wv + bv  (bf16)
    gemm_mfma<false, true, false><<<dim3(2, mt), 256, 0, stream>>>(
        (const ushort_t*)src_b, (const ushort_t*)wvt, bv, nullptr, val_b, M, 256, 256);

    // offs = q @ wo + bo  (f32)
    gemm_mfma<false, false, false><<<dim3(3, mt), 256, 0, stream>>>(
        (const ushort_t*)q_b, (const ushort_t*)wot, bo, nullptr, offs, M, 320, 256);

    // logits = q @ wa + ba  (f32)
    gemm_mfma<false, false, false><<<dim3(2, mt), 256, 0, stream>>>(
        (const ushort_t*)q_b, (const ushort_t*)wat, ba, nullptr, logits, M, 160, 256);

    // deformable attention -> acc_b (bf16)
    msda_kernel<<<M, 256, 0, stream>>>(offs, logits, refp,
                                       (const ushort_t*)val_b, acc_b, L);

    // y = acc @ wout + bout + src  (f32)
    gemm_mfma<false, false, true><<<dim3(2, mt), 256, 0, stream>>>(
        (const ushort_t*)acc_b, (const ushort_t*)woutt, bout, src, y, M, 256, 256);

    // x = LN1(y)  -> x_f (f32 resid) + x_b (bf16 GEMM input)
    ln_kernel<true><<<M, 256, 0, stream>>>(y, ln1g, ln1b, x_f, x_b);

    // h = relu(x @ w1 + b1)  (bf16)
    gemm_mfma<true, true, false><<<dim3(16, mt), 256, 0, stream>>>(
        (const ushort_t*)x_b, (const ushort_t*)w1t, b1, nullptr, h_b, M, FF, 256);

    // z = h @ w2 + b2 + x  (f32)
    gemm_mfma<false, false, true><<<dim3(2, mt), 256, 0, stream>>>(
        (const ushort_t*)h_b, (const ushort_t*)w2t, b2, x_f, z, M, 256, FF);

    // out = LN2(z)
    ln_kernel<false><<<M, 256, 0, stream>>>(z, ln2g, ln2b, (float*)d_out, nullptr);
}

// Round 4
// 587.216 us; speedup vs baseline: 3.3218x; 1.4169x over previous
//
#include <hip/hip_runtime.h>
#include <hip/hip_bf16.h>

typedef __hip_bfloat16 bf16;
typedef unsigned short ushort_t;
typedef __attribute__((ext_vector_type(8))) short bf16x8;
typedef __attribute__((ext_vector_type(4))) float f32x4;

__device__ __forceinline__ float us2f(unsigned short u) {
    unsigned int x = ((unsigned int)u) << 16;
    return __uint_as_float(x);
}

// ---------------------------------------------------------------------------
// q_b = bf16(a + b)
// ---------------------------------------------------------------------------
__global__ __launch_bounds__(256) void add_cast_kernel(
    const float* __restrict__ a, const float* __restrict__ b,
    bf16* __restrict__ o, int n)
{
    int i = blockIdx.x * 256 + threadIdx.x;
    if (i < n) o[i] = __float2bfloat16(a[i] + b[i]);
}

// ---------------------------------------------------------------------------
// o = bf16(a)
// ---------------------------------------------------------------------------
__global__ __launch_bounds__(256) void cast_kernel(
    const float* __restrict__ a, bf16* __restrict__ o, int n)
{
    int i = blockIdx.x * 256 + threadIdx.x;
    if (i < n) o[i] = __float2bfloat16(a[i]);
}

// ---------------------------------------------------------------------------
// Wt[n][k] = bf16(W[k][n])   (32x32 LDS tile transpose)
// ---------------------------------------------------------------------------
__global__ __launch_bounds__(256) void transpose_cast_kernel(
    const float* __restrict__ W, bf16* __restrict__ Wt, int K, int N)
{
    __shared__ float tile[32][33];
    const int tx = threadIdx.x & 31, ty = threadIdx.x >> 5;  // 32 x 8
    const int nb = blockIdx.x * 32, kb = blockIdx.y * 32;
    #pragma unroll
    for (int i = 0; i < 32; i += 8) {
        int k = kb + ty + i, n = nb + tx;
        tile[ty + i][tx] = (k < K && n < N) ? W[(size_t)k * N + n] : 0.f;
    }
    __syncthreads();
    #pragma unroll
    for (int i = 0; i < 32; i += 8) {
        int n = nb + ty + i, k = kb + tx;
        if (n < N && k < K)
            Wt[(size_t)n * K + k] = __float2bfloat16(tile[tx][ty + i]);
    }
}

// ---------------------------------------------------------------------------
// MFMA bf16 GEMM: out[M,N] = A[M,K] @ Bt[N,K]^T + bias (+resid) (relu?)
// 128x128 block tile, 4 waves, each wave 64x64 = 4x4 MFMA 16x16x32 tiles.
// ---------------------------------------------------------------------------
template<bool RELU, bool OUT_BF16, bool HAS_RESID>
__global__ __launch_bounds__(256) void gemm_mfma(
    const ushort_t* __restrict__ A,    // [M][K] bf16
    const ushort_t* __restrict__ Bt,   // [N][K] bf16
    const float* __restrict__ bias,    // [N] f32
    const float* __restrict__ resid,   // [M][N] f32
    void* __restrict__ outv, int M, int N, int K)
{
    __shared__ ushort_t Asmem[128 * 40];
    __shared__ ushort_t Bsmem[128 * 40];
    const int tid = threadIdx.x;
    const int lane = tid & 63;
    const int wave = tid >> 6;
    const int quad = lane >> 4;
    const int l16 = lane & 15;
    const int wm = wave >> 1, wn = wave & 1;
    const int m0 = blockIdx.y * 128;
    const int n0 = blockIdx.x * 128;

    const int r0 = tid >> 2;
    const int kg = (tid & 3) * 8;

    f32x4 acc[4][4] = {};

    for (int k0 = 0; k0 < K; k0 += 32) {
        #pragma unroll
        for (int half = 0; half < 2; ++half) {
            const int r = r0 + half * 64;
            int4 av = {0, 0, 0, 0};
            const int m = m0 + r;
            if (m < M)
                av = *reinterpret_cast<const int4*>(A + (size_t)m * K + k0 + kg);
            *reinterpret_cast<int4*>(&Asmem[r * 40 + kg]) = av;

            int4 bv = {0, 0, 0, 0};
            const int n = n0 + r;
            if (n < N)
                bv = *reinterpret_cast<const int4*>(Bt + (size_t)n * K + k0 + kg);
            *reinterpret_cast<int4*>(&Bsmem[r * 40 + kg]) = bv;
        }
        __syncthreads();

        bf16x8 af[4], bfr[4];
        #pragma unroll
        for (int i = 0; i < 4; ++i) {
            const int row = wm * 64 + i * 16 + l16;
            af[i] = *reinterpret_cast<const bf16x8*>(&Asmem[row * 40 + quad * 8]);
        }
        #pragma unroll
        for (int j = 0; j < 4; ++j) {
            const int row = wn * 64 + j * 16 + l16;
            bfr[j] = *reinterpret_cast<const bf16x8*>(&Bsmem[row * 40 + quad * 8]);
        }
        #pragma unroll
        for (int i = 0; i < 4; ++i)
            #pragma unroll
            for (int j = 0; j < 4; ++j)
                acc[i][j] = __builtin_amdgcn_mfma_f32_16x16x32_bf16(
                    af[i], bfr[j], acc[i][j], 0, 0, 0);
        __syncthreads();
    }

    // epilogue: C/D layout col = lane&15, row = quad*4 + reg  [m89/m91]
    #pragma unroll
    for (int i = 0; i < 4; ++i) {
        const int mbase = m0 + wm * 64 + i * 16 + quad * 4;
        #pragma unroll
        for (int j = 0; j < 4; ++j) {
            const int n = n0 + wn * 64 + j * 16 + l16;
            if (n >= N) continue;
            const float bval = bias[n];
            #pragma unroll
            for (int r = 0; r < 4; ++r) {
                const int m = mbase + r;
                if (m >= M) continue;
                float v = acc[i][j][r] + bval;
                if (HAS_RESID) v += resid[(size_t)m * N + n];
                if (RELU) v = fmaxf(v, 0.f);
                if (OUT_BF16)
                    ((bf16*)outv)[(size_t)m * N + n] = __float2bfloat16(v);
                else
                    ((float*)outv)[(size_t)m * N + n] = v;
            }
        }
    }
}

// ---------------------------------------------------------------------------
// MS-deformable attention v2.
// Block = 256 threads = 8 queries x 32 threads.
// Per query: 32 threads = 8 heads x 4 channel-groups; each lane handles 8
// channels via one 16-B gather per corner. Coordinate math replicated only
// 4x (vs 32x in v1); attention*bilinear weight folded to one scalar/corner.
// ---------------------------------------------------------------------------
__global__ __launch_bounds__(256) void msda_kernel_v2(
    const float* __restrict__ offs,      // [M,320]
    const float* __restrict__ logits,    // [M,160]
    const float* __restrict__ refp,      // [M,10]
    const ushort_t* __restrict__ value,  // [M,256] bf16 = (B,L,H,32)
    bf16* __restrict__ out,              // [M,256] bf16
    int M, int L)
{
    const int tid = threadIdx.x;
    const int qi  = tid >> 5;      // query slot 0..7
    const int g   = tid & 31;
    const int h   = g >> 2;        // head 0..7
    const int sub = g & 3;         // channel group (8 ch each)
    const int qbase = blockIdx.x * 8;
    const int bq = qbase + qi;

    __shared__ float s_off[8][320];
    __shared__ float s_attn[8][160];
    __shared__ float s_ref[8][10];

    for (int i = tid; i < 8 * 320; i += 256) {
        int q = i >> 8 == 0 ? 0 : i / 320;  // avoid div? keep simple below
        q = i / 320;
        int j = i - q * 320;
        int qq = qbase + q;
        s_off[q][j] = (qq < M) ? offs[(size_t)qq * 320 + j] : 0.f;
    }
    for (int i = tid; i < 8 * 160; i += 256) {
        int q = i / 160, j = i - q * 160;
        int qq = qbase + q;
        s_attn[q][j] = (qq < M) ? logits[(size_t)qq * 160 + j] : 0.f;
    }
    if (tid < 80) {
        int q = tid / 10, j = tid - q * 10;
        int qq = qbase + q;
        s_ref[q][j] = (qq < M) ? refp[(size_t)qq * 10 + j] : 0.f;
    }
    __syncthreads();

    // softmax: thread t<64 handles (query t>>3, head t&7)
    if (tid < 64) {
        float* a = &s_attn[tid >> 3][(tid & 7) * 20];
        float mx = -1e30f;
        #pragma unroll
        for (int i = 0; i < 20; ++i) mx = fmaxf(mx, a[i]);
        float ssum = 0.f;
        #pragma unroll
        for (int i = 0; i < 20; ++i) {
            float e = __expf(a[i] - mx);
            a[i] = e;
            ssum += e;
        }
        float inv = 1.f / ssum;
        #pragma unroll
        for (int i = 0; i < 20; ++i) a[i] *= inv;
    }
    __syncthreads();

    if (bq >= M) return;
    const int b = bq / L;

    const int HW[5] = {100, 50, 25, 13, 7};
    const int st[5] = {0, 10000, 12500, 13125, 13294};

    // value row base for this (b, head, channel-group)
    const ushort_t* vbase = value + (size_t)b * L * 256 + h * 32 + sub * 8;

    float acc[8] = {};

    #pragma unroll
    for (int l = 0; l < 5; ++l) {
        const int Wi = HW[l], Hi = HW[l], s0 = st[l];
        const float Wf = (float)Wi, Hf = (float)Hi;
        const float pxb = fmaf(s_ref[qi][l * 2 + 0], Wf, -0.5f);
        const float pyb = fmaf(s_ref[qi][l * 2 + 1], Hf, -0.5f);
        #pragma unroll
        for (int p = 0; p < 4; ++p) {
            const float px = pxb + s_off[qi][h * 40 + l * 8 + p * 2 + 0];
            const float py = pyb + s_off[qi][h * 40 + l * 8 + p * 2 + 1];
            const float x0 = floorf(px);
            const float y0 = floorf(py);
            const float lx = px - x0;
            const float ly = py - y0;
            const int x0i = (int)x0;
            const int y0i = (int)y0;
            const float a = s_attn[qi][h * 20 + l * 4 + p];

            #pragma unroll
            for (int dy = 0; dy < 2; ++dy) {
                const int yi = y0i + dy;
                if (yi < 0 || yi >= Hi) continue;
                const float wy = dy ? ly : (1.f - ly);
                #pragma unroll
                for (int dx = 0; dx < 2; ++dx) {
                    const int xi = x0i + dx;
                    if (xi < 0 || xi >= Wi) continue;
                    const float wx = dx ? lx : (1.f - lx);
                    const float w = a * wx * wy;
                    const int4 u = *reinterpret_cast<const int4*>(
                        vbase + (size_t)(s0 + yi * Wi + xi) * 256);
                    acc[0] = fmaf(w, __uint_as_float((unsigned)u.x << 16), acc[0]);
                    acc[1] = fmaf(w, __uint_as_float((unsigned)u.x & 0xffff0000u), acc[1]);
                    acc[2] = fmaf(w, __uint_as_float((unsigned)u.y << 16), acc[2]);
                    acc[3] = fmaf(w, __uint_as_float((unsigned)u.y & 0xffff0000u), acc[3]);
                    acc[4] = fmaf(w, __uint_as_float((unsigned)u.z << 16), acc[4]);
                    acc[5] = fmaf(w, __uint_as_float((unsigned)u.z & 0xffff0000u), acc[5]);
                    acc[6] = fmaf(w, __uint_as_float((unsigned)u.w << 16), acc[6]);
                    acc[7] = fmaf(w, __uint_as_float((unsigned)u.w & 0xffff0000u), acc[7]);
                }
            }
        }
    }

    // pack 8 accs -> 4 dwords, one 16-B store
    ushort_t o[8];
    #pragma unroll
    for (int i = 0; i < 8; ++i)
        o[i] = ((__hip_bfloat16_raw)__float2bfloat16(acc[i])).x;
    int4 pkt;
    pkt.x = (int)o[0] | ((int)o[1] << 16);
    pkt.y = (int)o[2] | ((int)o[3] << 16);
    pkt.z = (int)o[4] | ((int)o[5] << 16);
    pkt.w = (int)o[6] | ((int)o[7] << 16);
    *reinterpret_cast<int4*>((ushort_t*)out + (size_t)bq * 256 + h * 32 + sub * 8) = pkt;
}

// ---------------------------------------------------------------------------
// LayerNorm (256). DUAL: also emit bf16 copy.
// ---------------------------------------------------------------------------
template<bool DUAL>
__global__ __launch_bounds__(256) void ln_kernel(
    const float* __restrict__ y, const float* __restrict__ g,
    const float* __restrict__ bta, float* __restrict__ outf,
    bf16* __restrict__ outb)
{
    const int row = blockIdx.x;
    const int tid = threadIdx.x;
    float v = y[(size_t)row * 256 + tid];
    float s = v, ss = v * v;
    #pragma unroll
    for (int o = 32; o > 0; o >>= 1) {
        s += __shfl_down(s, o);
        ss += __shfl_down(ss, o);
    }
    __shared__ float red[8];
    const int wid = tid >> 6, lane = tid & 63;
    if (lane == 0) { red[wid] = s; red[4 + wid] = ss; }
    __syncthreads();
    const float S = red[0] + red[1] + red[2] + red[3];
    const float SS = red[4] + red[5] + red[6] + red[7];
    const float mean = S * (1.f / 256.f);
    const float var = SS * (1.f / 256.f) - mean * mean;
    const float rs = rsqrtf(var + 1e-5f);
    const float o = (v - mean) * rs * g[tid] + bta[tid];
    outf[(size_t)row * 256 + tid] = o;
    if (DUAL) outb[(size_t)row * 256 + tid] = __float2bfloat16(o);
}

// ---------------------------------------------------------------------------
extern "C" void kernel_launch(void* const* d_in, const int* in_sizes, int n_in,
                              void* d_out, int out_size, void* d_ws, size_t ws_size,
                              hipStream_t stream)
{
    const int B = 2, L = 13343, C = 256, FF = 2048;
    const int M = B * L;  // 26686

    const float* src  = (const float*)d_in[0];
    const float* pos  = (const float*)d_in[1];
    const float* refp = (const float*)d_in[2];
    const float* wv   = (const float*)d_in[3];
    const float* bv   = (const float*)d_in[4];
    const float* wo   = (const float*)d_in[5];
    const float* bo   = (const float*)d_in[6];
    const float* wa   = (const float*)d_in[7];
    const float* ba   = (const float*)d_in[8];
    const float* wout = (const float*)d_in[9];
    const float* bout = (const float*)d_in[10];
    const float* ln1g = (const float*)d_in[11];
    const float* ln1b = (const float*)d_in[12];
    const float* w1   = (const float*)d_in[13];
    const float* b1   = (const float*)d_in[14];
    const float* w2   = (const float*)d_in[15];
    const float* b2   = (const float*)d_in[16];
    const float* ln2g = (const float*)d_in[17];
    const float* ln2b = (const float*)d_in[18];

    char* ws = (char*)d_ws;
    const size_t MB = 1ull << 20;
    // ---- workspace overlay (peak ~183 MB) ----
    bf16*  src_b  = (bf16*)(ws + 0);         // 13.7 MB
    bf16*  q_b    = (bf16*)(ws + 14 * MB);   // 13.7
    bf16*  val_b  = (bf16*)(ws + 28 * MB);   // 13.7
    float* offs   = (float*)(ws + 42 * MB);  // 34.2
    float* logits = (float*)(ws + 77 * MB);  // 17.1 -> ends 94.1
    bf16*  acc_b  = (bf16*)(ws + 95 * MB);   // 13.7 -> ends 108.7
    bf16*  h_b    = (bf16*)(ws + 0);         // M*2048 bf16 = 109.3 MB (overlays dead)
    float* y      = (float*)(ws + 110 * MB); // 27.3 (dead after LN1)
    float* z      = (float*)(ws + 110 * MB); // overlays y
    bf16*  x_b    = (bf16*)(ws + 138 * MB);  // 13.7
    float* x_f    = (float*)(ws + 152 * MB); // 27.3 -> ends 179.3
    bf16* wvt   = (bf16*)(ws + 180 * MB);
    bf16* wot   = wvt + 256 * 256;
    bf16* wat   = wot + 320 * 256;
    bf16* woutt = wat + 160 * 256;
    bf16* w1t   = woutt + 256 * 256;
    bf16* w2t   = w1t + 2048 * 256;          // ends ~182.6 MB
    (void)ws_size; (void)n_in; (void)in_sizes; (void)out_size;

    const int mt = (M + 127) / 128;  // 209

    // ---- weight transpose-casts ----
    transpose_cast_kernel<<<dim3(8, 8),   256, 0, stream>>>(wv,   wvt,   256, 256);
    transpose_cast_kernel<<<dim3(10, 8),  256, 0, stream>>>(wo,   wot,   256, 320);
    transpose_cast_kernel<<<dim3(5, 8),   256, 0, stream>>>(wa,   wat,   256, 160);
    transpose_cast_kernel<<<dim3(8, 8),   256, 0, stream>>>(wout, woutt, 256, 256);
    transpose_cast_kernel<<<dim3(64, 8),  256, 0, stream>>>(w1,   w1t,   256, 2048);
    transpose_cast_kernel<<<dim3(8, 64),  256, 0, stream>>>(w2,   w2t,   2048, 256);

    // ---- activation casts ----
    cast_kernel<<<(M * C + 255) / 256, 256, 0, stream>>>(src, src_b, M * C);
    add_cast_kernel<<<(M * C + 255) / 256, 256, 0, stream>>>(src, pos, q_b, M * C);

    // value = src @ wv + bv  (bf16)
    gemm_mfma<false, true, false><<<dim3(2, mt), 256, 0, stream>>>(
        (const ushort_t*)src_b, (const ushort_t*)wvt, bv, nullptr, val_b, M, 256, 256);

    // offs = q @ wo + bo  (f32)
    gemm_mfma<false, false, false><<<dim3(3, mt), 256, 0, stream>>>(
        (const ushort_t*)q_b, (const ushort_t*)wot, bo, nullptr, offs, M, 320, 256);

    // logits = q @ wa + ba  (f32)
    gemm_mfma<false, false, false><<<dim3(2, mt), 256, 0, stream>>>(
        (const ushort_t*)q_b, (const ushort_t*)wat, ba, nullptr, logits, M, 160, 256);

    // deformable attention -> acc_b (bf16)
    msda_kernel_v2<<<(M + 7) / 8, 256, 0, stream>>>(
        offs, logits, refp, (const ushort_t*)val_b, acc_b, M, L);

    // y = acc @ wout + bout + src  (f32)
    gemm_mfma<false, false, true><<<dim3(2, mt), 256, 0, stream>>>(
        (const ushort_t*)acc_b, (const ushort_t*)woutt, bout, src, y, M, 256, 256);

    // x = LN1(y)  -> x_f (f32 resid) + x_b (bf16 GEMM input)
    ln_kernel<true><<<M, 256, 0, stream>>>(y, ln1g, ln1b, x_f, x_b);

    // h = relu(x @ w1 + b1)  (bf16)
    gemm_mfma<true, true, false><<<dim3(16, mt), 256, 0, stream>>>(
        (const ushort_t*)x_b, (const ushort_t*)w1t, b1, nullptr, h_b, M, FF, 256);

    // z = h @ w2 + b2 + x  (f32)
    gemm_mfma<false, false, true><<<dim3(2, mt), 256, 0, stream>>>(
        (const ushort_t*)h_b, (const ushort_t*)w2t, b2, x_f, z, M, 256, FF);

    // out = LN2(z)
    ln_kernel<false><<<M, 256, 0, stream>>>(z, ln2g, ln2b, (float*)d_out, nullptr);
}

// Round 5
// 530.022 us; speedup vs baseline: 3.6803x; 1.1079x over previous
//
#include <hip/hip_runtime.h>
#include <hip/hip_bf16.h>

typedef __hip_bfloat16 bf16;
typedef unsigned short ushort_t;
typedef __attribute__((ext_vector_type(8))) short bf16x8;
typedef __attribute__((ext_vector_type(4))) float f32x4;

__device__ __forceinline__ float us2f(unsigned short u) {
    unsigned int x = ((unsigned int)u) << 16;
    return __uint_as_float(x);
}

// async global->LDS, 16 B per lane. LDS dest = wave-uniform base + lane*16.
__device__ __forceinline__ void gl_lds16(const ushort_t* g, ushort_t* l) {
    __builtin_amdgcn_global_load_lds(
        (const __attribute__((address_space(1))) void*)g,
        (__attribute__((address_space(3))) void*)l, 16, 0, 0);
}

// ---------------------------------------------------------------------------
__global__ __launch_bounds__(256) void add_cast_kernel(
    const float* __restrict__ a, const float* __restrict__ b,
    bf16* __restrict__ o, int n)
{
    int i = blockIdx.x * 256 + threadIdx.x;
    if (i < n) o[i] = __float2bfloat16(a[i] + b[i]);
}

__global__ __launch_bounds__(256) void cast_kernel(
    const float* __restrict__ a, bf16* __restrict__ o, int n)
{
    int i = blockIdx.x * 256 + threadIdx.x;
    if (i < n) o[i] = __float2bfloat16(a[i]);
}

__global__ __launch_bounds__(256) void concat_bias_kernel(
    const float* __restrict__ a, const float* __restrict__ b,
    float* __restrict__ o)
{
    int i = blockIdx.x * 256 + threadIdx.x;
    if (i < 320) o[i] = a[i];
    else if (i < 480) o[i] = b[i - 320];
}

// ---------------------------------------------------------------------------
// Wt[n][k] = bf16(W[k][n])   (32x32 LDS tile transpose)
// ---------------------------------------------------------------------------
__global__ __launch_bounds__(256) void transpose_cast_kernel(
    const float* __restrict__ W, bf16* __restrict__ Wt, int K, int N)
{
    __shared__ float tile[32][33];
    const int tx = threadIdx.x & 31, ty = threadIdx.x >> 5;  // 32 x 8
    const int nb = blockIdx.x * 32, kb = blockIdx.y * 32;
    #pragma unroll
    for (int i = 0; i < 32; i += 8) {
        int k = kb + ty + i, n = nb + tx;
        tile[ty + i][tx] = (k < K && n < N) ? W[(size_t)k * N + n] : 0.f;
    }
    __syncthreads();
    #pragma unroll
    for (int i = 0; i < 32; i += 8) {
        int n = nb + ty + i, k = kb + tx;
        if (n < N && k < K)
            Wt[(size_t)n * K + k] = __float2bfloat16(tile[tx][ty + i]);
    }
}

// ---------------------------------------------------------------------------
// MFMA bf16 GEMM (m97-style): out[M,N] = A[M,K] @ Bt[N,K]^T + bias (+resid)
// 128x128 tile, BK=32, global_load_lds(16B) staging into unpadded LDS
// (row stride 32 shorts = 64 B), 4 waves x (4x4) 16x16x32 MFMA.
// M/N edges: clamp gather row (garbage discarded in epilogue).
// ---------------------------------------------------------------------------
template<bool RELU, bool OUT_BF16, bool HAS_RESID>
__global__ __launch_bounds__(256) void gemm_mfma(
    const ushort_t* __restrict__ A,    // [M][K] bf16
    const ushort_t* __restrict__ Bt,   // [N][K] bf16
    const float* __restrict__ bias,    // [N] f32
    const float* __restrict__ resid,   // [M][N] f32
    void* __restrict__ outv, int M, int N, int K)
{
    __shared__ ushort_t Asmem[128 * 32];
    __shared__ ushort_t Bsmem[128 * 32];
    const int tid = threadIdx.x;
    const int lane = tid & 63;
    const int wave = tid >> 6;
    const int quad = lane >> 4;
    const int l16 = lane & 15;
    const int wm = wave >> 1, wn = wave & 1;
    const int m0 = blockIdx.y * 128;
    const int n0 = blockIdx.x * 128;

    const int srow = lane >> 2;       // 0..15 row within 16-row group
    const int kch  = (lane & 3) * 8;  // k element offset (16 B chunks)

    f32x4 acc[4][4] = {};

    for (int k0 = 0; k0 < K; k0 += 32) {
        #pragma unroll
        for (int i = 0; i < 2; ++i) {
            const int rbase = wave * 32 + i * 16;
            const int r = rbase + srow;
            int mA = m0 + r; if (mA > M - 1) mA = M - 1;
            int nB = n0 + r; if (nB > N - 1) nB = N - 1;
            gl_lds16(A  + (size_t)mA * K + k0 + kch, &Asmem[rbase * 32]);
            gl_lds16(Bt + (size_t)nB * K + k0 + kch, &Bsmem[rbase * 32]);
        }
        __syncthreads();

        bf16x8 af[4], bfr[4];
        #pragma unroll
        for (int i = 0; i < 4; ++i) {
            const int row = wm * 64 + i * 16 + l16;
            af[i] = *reinterpret_cast<const bf16x8*>(&Asmem[row * 32 + quad * 8]);
        }
        #pragma unroll
        for (int j = 0; j < 4; ++j) {
            const int row = wn * 64 + j * 16 + l16;
            bfr[j] = *reinterpret_cast<const bf16x8*>(&Bsmem[row * 32 + quad * 8]);
        }
        #pragma unroll
        for (int i = 0; i < 4; ++i)
            #pragma unroll
            for (int j = 0; j < 4; ++j)
                acc[i][j] = __builtin_amdgcn_mfma_f32_16x16x32_bf16(
                    af[i], bfr[j], acc[i][j], 0, 0, 0);
        __syncthreads();
    }

    // epilogue: C/D layout col = lane&15, row = quad*4 + reg  [m89/m91]
    #pragma unroll
    for (int i = 0; i < 4; ++i) {
        const int mbase = m0 + wm * 64 + i * 16 + quad * 4;
        #pragma unroll
        for (int j = 0; j < 4; ++j) {
            const int n = n0 + wn * 64 + j * 16 + l16;
            if (n >= N) continue;
            const float bval = bias[n];
            #pragma unroll
            for (int r = 0; r < 4; ++r) {
                const int m = mbase + r;
                if (m >= M) continue;
                float v = acc[i][j][r] + bval;
                if (HAS_RESID) v += resid[(size_t)m * N + n];
                if (RELU) v = fmaxf(v, 0.f);
                if (OUT_BF16)
                    ((bf16*)outv)[(size_t)m * N + n] = __float2bfloat16(v);
                else
                    ((float*)outv)[(size_t)m * N + n] = v;
            }
        }
    }
}

// ---------------------------------------------------------------------------
// MS-deformable attention v2. Block = 8 queries x 32 threads.
// og = combined [M][480] buffer: offsets at +0 (320), logits at +320 (160).
// ---------------------------------------------------------------------------
__global__ __launch_bounds__(256) void msda_kernel_v2(
    const float* __restrict__ og,        // [M,480]
    const float* __restrict__ refp,      // [M,10]
    const ushort_t* __restrict__ value,  // [M,256] bf16 = (B,L,H,32)
    bf16* __restrict__ out,              // [M,256] bf16
    int M, int L)
{
    const int tid = threadIdx.x;
    const int qi  = tid >> 5;
    const int g   = tid & 31;
    const int h   = g >> 2;
    const int sub = g & 3;
    const int qbase = blockIdx.x * 8;
    const int bq = qbase + qi;

    __shared__ float s_off[8][320];
    __shared__ float s_attn[8][160];
    __shared__ float s_ref[8][10];

    for (int i = tid; i < 8 * 320; i += 256) {
        int q = i / 320, j = i - q * 320;
        int qq = qbase + q;
        s_off[q][j] = (qq < M) ? og[(size_t)qq * 480 + j] : 0.f;
    }
    for (int i = tid; i < 8 * 160; i += 256) {
        int q = i / 160, j = i - q * 160;
        int qq = qbase + q;
        s_attn[q][j] = (qq < M) ? og[(size_t)qq * 480 + 320 + j] : 0.f;
    }
    if (tid < 80) {
        int q = tid / 10, j = tid - q * 10;
        int qq = qbase + q;
        s_ref[q][j] = (qq < M) ? refp[(size_t)qq * 10 + j] : 0.f;
    }
    __syncthreads();

    if (tid < 64) {
        float* a = &s_attn[tid >> 3][(tid & 7) * 20];
        float mx = -1e30f;
        #pragma unroll
        for (int i = 0; i < 20; ++i) mx = fmaxf(mx, a[i]);
        float ssum = 0.f;
        #pragma unroll
        for (int i = 0; i < 20; ++i) {
            float e = __expf(a[i] - mx);
            a[i] = e;
            ssum += e;
        }
        float inv = 1.f / ssum;
        #pragma unroll
        for (int i = 0; i < 20; ++i) a[i] *= inv;
    }
    __syncthreads();

    if (bq >= M) return;
    const int b = bq / L;

    const int HW[5] = {100, 50, 25, 13, 7};
    const int st[5] = {0, 10000, 12500, 13125, 13294};

    const ushort_t* vbase = value + (size_t)b * L * 256 + h * 32 + sub * 8;

    float acc[8] = {};

    #pragma unroll
    for (int l = 0; l < 5; ++l) {
        const int Wi = HW[l], Hi = HW[l], s0 = st[l];
        const float Wf = (float)Wi, Hf = (float)Hi;
        const float pxb = fmaf(s_ref[qi][l * 2 + 0], Wf, -0.5f);
        const float pyb = fmaf(s_ref[qi][l * 2 + 1], Hf, -0.5f);
        #pragma unroll
        for (int p = 0; p < 4; ++p) {
            const float px = pxb + s_off[qi][h * 40 + l * 8 + p * 2 + 0];
            const float py = pyb + s_off[qi][h * 40 + l * 8 + p * 2 + 1];
            const float x0 = floorf(px);
            const float y0 = floorf(py);
            const float lx = px - x0;
            const float ly = py - y0;
            const int x0i = (int)x0;
            const int y0i = (int)y0;
            const float a = s_attn[qi][h * 20 + l * 4 + p];

            #pragma unroll
            for (int dy = 0; dy < 2; ++dy) {
                const int yi = y0i + dy;
                if (yi < 0 || yi >= Hi) continue;
                const float wy = dy ? ly : (1.f - ly);
                #pragma unroll
                for (int dx = 0; dx < 2; ++dx) {
                    const int xi = x0i + dx;
                    if (xi < 0 || xi >= Wi) continue;
                    const float wx = dx ? lx : (1.f - lx);
                    const float w = a * wx * wy;
                    const int4 u = *reinterpret_cast<const int4*>(
                        vbase + (size_t)(s0 + yi * Wi + xi) * 256);
                    acc[0] = fmaf(w, __uint_as_float((unsigned)u.x << 16), acc[0]);
                    acc[1] = fmaf(w, __uint_as_float((unsigned)u.x & 0xffff0000u), acc[1]);
                    acc[2] = fmaf(w, __uint_as_float((unsigned)u.y << 16), acc[2]);
                    acc[3] = fmaf(w, __uint_as_float((unsigned)u.y & 0xffff0000u), acc[3]);
                    acc[4] = fmaf(w, __uint_as_float((unsigned)u.z << 16), acc[4]);
                    acc[5] = fmaf(w, __uint_as_float((unsigned)u.z & 0xffff0000u), acc[5]);
                    acc[6] = fmaf(w, __uint_as_float((unsigned)u.w << 16), acc[6]);
                    acc[7] = fmaf(w, __uint_as_float((unsigned)u.w & 0xffff0000u), acc[7]);
                }
            }
        }
    }

    ushort_t o[8];
    #pragma unroll
    for (int i = 0; i < 8; ++i)
        o[i] = ((__hip_bfloat16_raw)__float2bfloat16(acc[i])).x;
    int4 pkt;
    pkt.x = (int)o[0] | ((int)o[1] << 16);
    pkt.y = (int)o[2] | ((int)o[3] << 16);
    pkt.z = (int)o[4] | ((int)o[5] << 16);
    pkt.w = (int)o[6] | ((int)o[7] << 16);
    *reinterpret_cast<int4*>((ushort_t*)out + (size_t)bq * 256 + h * 32 + sub * 8) = pkt;
}

// ---------------------------------------------------------------------------
template<bool DUAL>
__global__ __launch_bounds__(256) void ln_kernel(
    const float* __restrict__ y, const float* __restrict__ g,
    const float* __restrict__ bta, float* __restrict__ outf,
    bf16* __restrict__ outb)
{
    const int row = blockIdx.x;
    const int tid = threadIdx.x;
    float v = y[(size_t)row * 256 + tid];
    float s = v, ss = v * v;
    #pragma unroll
    for (int o = 32; o > 0; o >>= 1) {
        s += __shfl_down(s, o);
        ss += __shfl_down(ss, o);
    }
    __shared__ float red[8];
    const int wid = tid >> 6, lane = tid & 63;
    if (lane == 0) { red[wid] = s; red[4 + wid] = ss; }
    __syncthreads();
    const float S = red[0] + red[1] + red[2] + red[3];
    const float SS = red[4] + red[5] + red[6] + red[7];
    const float mean = S * (1.f / 256.f);
    const float var = SS * (1.f / 256.f) - mean * mean;
    const float rs = rsqrtf(var + 1e-5f);
    const float o = (v - mean) * rs * g[tid] + bta[tid];
    outf[(size_t)row * 256 + tid] = o;
    if (DUAL) outb[(size_t)row * 256 + tid] = __float2bfloat16(o);
}

// ---------------------------------------------------------------------------
extern "C" void kernel_launch(void* const* d_in, const int* in_sizes, int n_in,
                              void* d_out, int out_size, void* d_ws, size_t ws_size,
                              hipStream_t stream)
{
    const int B = 2, L = 13343, C = 256, FF = 2048;
    const int M = B * L;  // 26686

    const float* src  = (const float*)d_in[0];
    const float* pos  = (const float*)d_in[1];
    const float* refp = (const float*)d_in[2];
    const float* wv   = (const float*)d_in[3];
    const float* bv   = (const float*)d_in[4];
    const float* wo   = (const float*)d_in[5];
    const float* bo   = (const float*)d_in[6];
    const float* wa   = (const float*)d_in[7];
    const float* ba   = (const float*)d_in[8];
    const float* wout = (const float*)d_in[9];
    const float* bout = (const float*)d_in[10];
    const float* ln1g = (const float*)d_in[11];
    const float* ln1b = (const float*)d_in[12];
    const float* w1   = (const float*)d_in[13];
    const float* b1   = (const float*)d_in[14];
    const float* w2   = (const float*)d_in[15];
    const float* b2   = (const float*)d_in[16];
    const float* ln2g = (const float*)d_in[17];
    const float* ln2b = (const float*)d_in[18];

    char* ws = (char*)d_ws;
    const size_t MB = 1ull << 20;
    // ---- workspace overlay (peak ~184 MB) ----
    bf16*  src_b  = (bf16*)(ws + 0);         // 13.7 MB
    bf16*  q_b    = (bf16*)(ws + 14 * MB);   // 13.7
    bf16*  val_b  = (bf16*)(ws + 28 * MB);   // 13.7
    float* og     = (float*)(ws + 42 * MB);  // M*480 f32 = 51.2 -> ends 93.2
    bf16*  acc_b  = (bf16*)(ws + 95 * MB);   // 13.7 -> ends 108.7
    bf16*  h_b    = (bf16*)(ws + 0);         // M*2048 bf16 = 109.3 (overlays dead)
    float* y      = (float*)(ws + 110 * MB); // 27.3 (dead after LN1)
    float* z      = (float*)(ws + 110 * MB); // overlays y
    bf16*  x_b    = (bf16*)(ws + 138 * MB);  // 13.7
    float* x_f    = (float*)(ws + 152 * MB); // 27.3 -> ends 179.3
    bf16* wvt    = (bf16*)(ws + 180 * MB);   // 256*256
    bf16* wcat   = wvt + 256 * 256;          // 480*256 (wo rows 0..319, wa 320..479)
    bf16* woutt  = wcat + 480 * 256;         // 256*256
    bf16* w1t    = woutt + 256 * 256;        // 2048*256
    bf16* w2t    = w1t + 2048 * 256;         // 256*2048
    float* bcat  = (float*)(w2t + 256 * 2048); // 480 f32, ends ~182.6 MB
    (void)ws_size; (void)n_in; (void)in_sizes; (void)out_size;

    const int mt = (M + 127) / 128;  // 209

    // ---- weight transpose-casts ----
    transpose_cast_kernel<<<dim3(8, 8),  256, 0, stream>>>(wv,   wvt,            256, 256);
    transpose_cast_kernel<<<dim3(10, 8), 256, 0, stream>>>(wo,   wcat,           256, 320);
    transpose_cast_kernel<<<dim3(5, 8),  256, 0, stream>>>(wa,   wcat + 320*256, 256, 160);
    transpose_cast_kernel<<<dim3(8, 8),  256, 0, stream>>>(wout, woutt,          256, 256);
    transpose_cast_kernel<<<dim3(64, 8), 256, 0, stream>>>(w1,   w1t,            256, 2048);
    transpose_cast_kernel<<<dim3(8, 64), 256, 0, stream>>>(w2,   w2t,            2048, 256);
    concat_bias_kernel<<<2, 256, 0, stream>>>(bo, ba, bcat);

    // ---- activation casts ----
    cast_kernel<<<(M * C + 255) / 256, 256, 0, stream>>>(src, src_b, M * C);
    add_cast_kernel<<<(M * C + 255) / 256, 256, 0, stream>>>(src, pos, q_b, M * C);

    // value = src @ wv + bv  (bf16)
    gemm_mfma<false, true, false><<<dim3(2, mt), 256, 0, stream>>>(
        (const ushort_t*)src_b, (const ushort_t*)wvt, bv, nullptr, val_b, M, 256, 256);

    // og = q @ [wo|wa] + [bo|ba]  (f32, N=480)
    gemm_mfma<false, false, false><<<dim3(4, mt), 256, 0, stream>>>(
        (const ushort_t*)q_b, (const ushort_t*)wcat, bcat, nullptr, og, M, 480, 256);

    // deformable attention -> acc_b (bf16)
    msda_kernel_v2<<<(M + 7) / 8, 256, 0, stream>>>(
        og, refp, (const ushort_t*)val_b, acc_b, M, L);

    // y = acc @ wout + bout + src  (f32)
    gemm_mfma<false, false, true><<<dim3(2, mt), 256, 0, stream>>>(
        (const ushort_t*)acc_b, (const ushort_t*)woutt, bout, src, y, M, 256, 256);

    // x = LN1(y)
    ln_kernel<true><<<M, 256, 0, stream>>>(y, ln1g, ln1b, x_f, x_b);

    // h = relu(x @ w1 + b1)  (bf16)
    gemm_mfma<true, true, false><<<dim3(16, mt), 256, 0, stream>>>(
        (const ushort_t*)x_b, (const ushort_t*)w1t, b1, nullptr, h_b, M, FF, 256);

    // z = h @ w2 + b2 + x  (f32)
    gemm_mfma<false, false, true><<<dim3(2, mt), 256, 0, stream>>>(
        (const ushort_t*)h_b, (const ushort_t*)w2t, b2, x_f, z, M, 256, FF);

    // out = LN2(z)
    ln_kernel<false><<<M, 256, 0, stream>>>(z, ln2g, ln2b, (float*)d_out, nullptr);
}

// Round 6
// 462.689 us; speedup vs baseline: 4.2159x; 1.1455x over previous
//
#include <hip/hip_runtime.h>
#include <hip/hip_bf16.h>

typedef __hip_bfloat16 bf16;
typedef unsigned short ushort_t;
typedef __attribute__((ext_vector_type(8))) short bf16x8;
typedef __attribute__((ext_vector_type(16))) float f32x16;

__device__ __forceinline__ float us2f(unsigned short u) {
    unsigned int x = ((unsigned int)u) << 16;
    return __uint_as_float(x);
}

// async global->LDS, 16 B per lane. LDS dest = wave-uniform base + lane*16.
__device__ __forceinline__ void gl_lds16(const ushort_t* g, ushort_t* l) {
    __builtin_amdgcn_global_load_lds(
        (const __attribute__((address_space(1))) void*)g,
        (__attribute__((address_space(3))) void*)l, 16, 0, 0);
}

// ---------------------------------------------------------------------------
// Fused input cast: src_b = bf16(src), q_b = bf16(src + pos)
// ---------------------------------------------------------------------------
__global__ __launch_bounds__(256) void cast2_kernel(
    const float* __restrict__ src, const float* __restrict__ pos,
    bf16* __restrict__ src_b, bf16* __restrict__ q_b, int n)
{
    int i = blockIdx.x * 256 + threadIdx.x;
    if (i < n) {
        float s = src[i];
        src_b[i] = __float2bfloat16(s);
        q_b[i]   = __float2bfloat16(s + pos[i]);
    }
}

// ---------------------------------------------------------------------------
// Fused weight prep: all transpose-casts + bias concat in ONE launch.
// Each block does one 32x32 tile (or the bias tail).
// ---------------------------------------------------------------------------
__global__ __launch_bounds__(256) void prep_kernel(
    const float* __restrict__ wv, const float* __restrict__ wo,
    const float* __restrict__ wa, const float* __restrict__ wout,
    const float* __restrict__ w1, const float* __restrict__ w2,
    const float* __restrict__ bo, const float* __restrict__ ba,
    bf16* __restrict__ wvt, bf16* __restrict__ wcat, bf16* __restrict__ woutt,
    bf16* __restrict__ w1t, bf16* __restrict__ w2t, float* __restrict__ bcat)
{
    __shared__ float tile[32][33];
    const int b = blockIdx.x;
    const float* W; bf16* Wt; int K, N, tb;
    if (b < 64)        { W = wv;   Wt = wvt;            K = 256;  N = 256;  tb = b; }
    else if (b < 144)  { W = wo;   Wt = wcat;           K = 256;  N = 320;  tb = b - 64; }
    else if (b < 184)  { W = wa;   Wt = wcat + 320*256; K = 256;  N = 160;  tb = b - 144; }
    else if (b < 248)  { W = wout; Wt = woutt;          K = 256;  N = 256;  tb = b - 184; }
    else if (b < 760)  { W = w1;   Wt = w1t;            K = 256;  N = 2048; tb = b - 248; }
    else if (b < 1272) { W = w2;   Wt = w2t;            K = 2048; N = 256;  tb = b - 760; }
    else {
        int i = (b - 1272) * 256 + threadIdx.x;
        if (i < 320) bcat[i] = bo[i];
        else if (i < 480) bcat[i] = ba[i - 320];
        return;
    }
    const int ntn = N >> 5;
    const int nb = (tb % ntn) * 32, kb = (tb / ntn) * 32;
    const int tx = threadIdx.x & 31, ty = threadIdx.x >> 5;  // 32 x 8
    #pragma unroll
    for (int i = 0; i < 32; i += 8) {
        int k = kb + ty + i, n = nb + tx;
        tile[ty + i][tx] = (k < K && n < N) ? W[(size_t)k * N + n] : 0.f;
    }
    __syncthreads();
    #pragma unroll
    for (int i = 0; i < 32; i += 8) {
        int n = nb + ty + i, k = kb + tx;
        if (n < N && k < K)
            Wt[(size_t)n * K + k] = __float2bfloat16(tile[tx][ty + i]);
    }
}

// ---------------------------------------------------------------------------
// MFMA bf16 GEMM v2: out[M,N] = A[M,K] @ Bt[N,K]^T + bias (+resid) (relu?)
// 128x128 tile, BK=32, global_load_lds(16B) staging, unpadded LDS (64-B rows),
// 4 waves x (2x2) 32x32x16 MFMA, hoisted incremental staging addresses.
// ---------------------------------------------------------------------------
template<bool RELU, bool OUT_BF16, bool HAS_RESID>
__global__ __launch_bounds__(256, 4) void gemm_mfma(
    const ushort_t* __restrict__ A,    // [M][K] bf16
    const ushort_t* __restrict__ Bt,   // [N][K] bf16
    const float* __restrict__ bias,    // [N] f32
    const float* __restrict__ resid,   // [M][N] f32
    void* __restrict__ outv, int M, int N, int K)
{
    __shared__ ushort_t Asmem[128 * 32];
    __shared__ ushort_t Bsmem[128 * 32];
    const int tid = threadIdx.x;
    const int lane = tid & 63;
    const int wave = tid >> 6;
    const int l32 = lane & 31;
    const int hi  = lane >> 5;
    const int wm = wave >> 1, wn = wave & 1;
    const int m0 = blockIdx.y * 128;
    const int n0 = blockIdx.x * 128;

    // staging: each wave stages 32 rows of A and B (2 calls of 16 rows each).
    // lane -> row (lane>>2) within group, k-chunk (lane&3)*8 elements.
    const int srow = lane >> 2;
    const int sch  = (lane & 3) * 8;

    const ushort_t* aP[2]; const ushort_t* bP[2];
    ushort_t* aL[2]; ushort_t* bL[2];
    #pragma unroll
    for (int i = 0; i < 2; ++i) {
        const int rbase = wave * 32 + i * 16;
        int mA = m0 + rbase + srow; if (mA > M - 1) mA = M - 1;
        int nB = n0 + rbase + srow; if (nB > N - 1) nB = N - 1;
        aP[i] = A  + (size_t)mA * K + sch;
        bP[i] = Bt + (size_t)nB * K + sch;
        aL[i] = &Asmem[rbase * 32];
        bL[i] = &Bsmem[rbase * 32];
    }

    f32x16 acc[2][2] = {};

    for (int k0 = 0; k0 < K; k0 += 32) {
        #pragma unroll
        for (int i = 0; i < 2; ++i) {
            gl_lds16(aP[i], aL[i]);
            gl_lds16(bP[i], bL[i]);
            aP[i] += 32; bP[i] += 32;
        }
        __syncthreads();

        #pragma unroll
        for (int kw = 0; kw < 2; ++kw) {
            bf16x8 af[2], bfr[2];
            #pragma unroll
            for (int i = 0; i < 2; ++i) {
                const int rowA = wm * 64 + i * 32 + l32;
                af[i] = *reinterpret_cast<const bf16x8*>(
                    &Asmem[rowA * 32 + kw * 16 + hi * 8]);
                const int rowB = wn * 64 + i * 32 + l32;
                bfr[i] = *reinterpret_cast<const bf16x8*>(
                    &Bsmem[rowB * 32 + kw * 16 + hi * 8]);
            }
            #pragma unroll
            for (int i = 0; i < 2; ++i)
                #pragma unroll
                for (int j = 0; j < 2; ++j)
                    acc[i][j] = __builtin_amdgcn_mfma_f32_32x32x16_bf16(
                        af[i], bfr[j], acc[i][j], 0, 0, 0);
        }
        __syncthreads();
    }

    // epilogue: 32x32 C/D layout col = lane&31, row = (r&3) + 8*(r>>2) + 4*hi
    #pragma unroll
    for (int i = 0; i < 2; ++i) {
        const int mb = m0 + wm * 64 + i * 32 + hi * 4;
        #pragma unroll
        for (int j = 0; j < 2; ++j) {
            const int n = n0 + wn * 64 + j * 32 + l32;
            if (n >= N) continue;
            const float bval = bias[n];
            #pragma unroll
            for (int r = 0; r < 16; ++r) {
                const int m = mb + (r & 3) + (r >> 2) * 8;
                if (m >= M) continue;
                float v = acc[i][j][r] + bval;
                if (HAS_RESID) v += resid[(size_t)m * N + n];
                if (RELU) v = fmaxf(v, 0.f);
                if (OUT_BF16)
                    ((bf16*)outv)[(size_t)m * N + n] = __float2bfloat16(v);
                else
                    ((float*)outv)[(size_t)m * N + n] = v;
            }
        }
    }
}

// ---------------------------------------------------------------------------
// MS-deformable attention v2. Block = 8 queries x 32 threads.
// og = combined [M][480] buffer: offsets at +0 (320), logits at +320 (160).
// ---------------------------------------------------------------------------
__global__ __launch_bounds__(256) void msda_kernel_v2(
    const float* __restrict__ og,        // [M,480]
    const float* __restrict__ refp,      // [M,10]
    const ushort_t* __restrict__ value,  // [M,256] bf16 = (B,L,H,32)
    bf16* __restrict__ out,              // [M,256] bf16
    int M, int L)
{
    const int tid = threadIdx.x;
    const int qi  = tid >> 5;
    const int g   = tid & 31;
    const int h   = g >> 2;
    const int sub = g & 3;
    const int qbase = blockIdx.x * 8;
    const int bq = qbase + qi;

    __shared__ float s_off[8][320];
    __shared__ float s_attn[8][160];
    __shared__ float s_ref[8][10];

    for (int i = tid; i < 8 * 320; i += 256) {
        int q = i / 320, j = i - q * 320;
        int qq = qbase + q;
        s_off[q][j] = (qq < M) ? og[(size_t)qq * 480 + j] : 0.f;
    }
    for (int i = tid; i < 8 * 160; i += 256) {
        int q = i / 160, j = i - q * 160;
        int qq = qbase + q;
        s_attn[q][j] = (qq < M) ? og[(size_t)qq * 480 + 320 + j] : 0.f;
    }
    if (tid < 80) {
        int q = tid / 10, j = tid - q * 10;
        int qq = qbase + q;
        s_ref[q][j] = (qq < M) ? refp[(size_t)qq * 10 + j] : 0.f;
    }
    __syncthreads();

    if (tid < 64) {
        float* a = &s_attn[tid >> 3][(tid & 7) * 20];
        float mx = -1e30f;
        #pragma unroll
        for (int i = 0; i < 20; ++i) mx = fmaxf(mx, a[i]);
        float ssum = 0.f;
        #pragma unroll
        for (int i = 0; i < 20; ++i) {
            float e = __expf(a[i] - mx);
            a[i] = e;
            ssum += e;
        }
        float inv = 1.f / ssum;
        #pragma unroll
        for (int i = 0; i < 20; ++i) a[i] *= inv;
    }
    __syncthreads();

    if (bq >= M) return;
    const int b = bq / L;

    const int HW[5] = {100, 50, 25, 13, 7};
    const int st[5] = {0, 10000, 12500, 13125, 13294};

    const ushort_t* vbase = value + (size_t)b * L * 256 + h * 32 + sub * 8;

    float acc[8] = {};

    #pragma unroll
    for (int l = 0; l < 5; ++l) {
        const int Wi = HW[l], Hi = HW[l], s0 = st[l];
        const float Wf = (float)Wi, Hf = (float)Hi;
        const float pxb = fmaf(s_ref[qi][l * 2 + 0], Wf, -0.5f);
        const float pyb = fmaf(s_ref[qi][l * 2 + 1], Hf, -0.5f);
        #pragma unroll
        for (int p = 0; p < 4; ++p) {
            const float px = pxb + s_off[qi][h * 40 + l * 8 + p * 2 + 0];
            const float py = pyb + s_off[qi][h * 40 + l * 8 + p * 2 + 1];
            const float x0 = floorf(px);
            const float y0 = floorf(py);
            const float lx = px - x0;
            const float ly = py - y0;
            const int x0i = (int)x0;
            const int y0i = (int)y0;
            const float a = s_attn[qi][h * 20 + l * 4 + p];

            #pragma unroll
            for (int dy = 0; dy < 2; ++dy) {
                const int yi = y0i + dy;
                if (yi < 0 || yi >= Hi) continue;
                const float wy = dy ? ly : (1.f - ly);
                #pragma unroll
                for (int dx = 0; dx < 2; ++dx) {
                    const int xi = x0i + dx;
                    if (xi < 0 || xi >= Wi) continue;
                    const float wx = dx ? lx : (1.f - lx);
                    const float w = a * wx * wy;
                    const int4 u = *reinterpret_cast<const int4*>(
                        vbase + (size_t)(s0 + yi * Wi + xi) * 256);
                    acc[0] = fmaf(w, __uint_as_float((unsigned)u.x << 16), acc[0]);
                    acc[1] = fmaf(w, __uint_as_float((unsigned)u.x & 0xffff0000u), acc[1]);
                    acc[2] = fmaf(w, __uint_as_float((unsigned)u.y << 16), acc[2]);
                    acc[3] = fmaf(w, __uint_as_float((unsigned)u.y & 0xffff0000u), acc[3]);
                    acc[4] = fmaf(w, __uint_as_float((unsigned)u.z << 16), acc[4]);
                    acc[5] = fmaf(w, __uint_as_float((unsigned)u.z & 0xffff0000u), acc[5]);
                    acc[6] = fmaf(w, __uint_as_float((unsigned)u.w << 16), acc[6]);
                    acc[7] = fmaf(w, __uint_as_float((unsigned)u.w & 0xffff0000u), acc[7]);
                }
            }
        }
    }

    ushort_t o[8];
    #pragma unroll
    for (int i = 0; i < 8; ++i)
        o[i] = ((__hip_bfloat16_raw)__float2bfloat16(acc[i])).x;
    int4 pkt;
    pkt.x = (int)o[0] | ((int)o[1] << 16);
    pkt.y = (int)o[2] | ((int)o[3] << 16);
    pkt.z = (int)o[4] | ((int)o[5] << 16);
    pkt.w = (int)o[6] | ((int)o[7] << 16);
    *reinterpret_cast<int4*>((ushort_t*)out + (size_t)bq * 256 + h * 32 + sub * 8) = pkt;
}

// ---------------------------------------------------------------------------
template<bool DUAL>
__global__ __launch_bounds__(256) void ln_kernel(
    const float* __restrict__ y, const float* __restrict__ g,
    const float* __restrict__ bta, float* __restrict__ outf,
    bf16* __restrict__ outb)
{
    const int row = blockIdx.x;
    const int tid = threadIdx.x;
    float v = y[(size_t)row * 256 + tid];
    float s = v, ss = v * v;
    #pragma unroll
    for (int o = 32; o > 0; o >>= 1) {
        s += __shfl_down(s, o);
        ss += __shfl_down(ss, o);
    }
    __shared__ float red[8];
    const int wid = tid >> 6, lane = tid & 63;
    if (lane == 0) { red[wid] = s; red[4 + wid] = ss; }
    __syncthreads();
    const float S = red[0] + red[1] + red[2] + red[3];
    const float SS = red[4] + red[5] + red[6] + red[7];
    const float mean = S * (1.f / 256.f);
    const float var = SS * (1.f / 256.f) - mean * mean;
    const float rs = rsqrtf(var + 1e-5f);
    const float o = (v - mean) * rs * g[tid] + bta[tid];
    outf[(size_t)row * 256 + tid] = o;
    if (DUAL) outb[(size_t)row * 256 + tid] = __float2bfloat16(o);
}

// ---------------------------------------------------------------------------
extern "C" void kernel_launch(void* const* d_in, const int* in_sizes, int n_in,
                              void* d_out, int out_size, void* d_ws, size_t ws_size,
                              hipStream_t stream)
{
    const int B = 2, L = 13343, C = 256, FF = 2048;
    const int M = B * L;  // 26686

    const float* src  = (const float*)d_in[0];
    const float* pos  = (const float*)d_in[1];
    const float* refp = (const float*)d_in[2];
    const float* wv   = (const float*)d_in[3];
    const float* bv   = (const float*)d_in[4];
    const float* wo   = (const float*)d_in[5];
    const float* bo   = (const float*)d_in[6];
    const float* wa   = (const float*)d_in[7];
    const float* ba   = (const float*)d_in[8];
    const float* wout = (const float*)d_in[9];
    const float* bout = (const float*)d_in[10];
    const float* ln1g = (const float*)d_in[11];
    const float* ln1b = (const float*)d_in[12];
    const float* w1   = (const float*)d_in[13];
    const float* b1   = (const float*)d_in[14];
    const float* w2   = (const float*)d_in[15];
    const float* b2   = (const float*)d_in[16];
    const float* ln2g = (const float*)d_in[17];
    const float* ln2b = (const float*)d_in[18];

    char* ws = (char*)d_ws;
    const size_t MB = 1ull << 20;
    // ---- workspace overlay (peak ~184 MB) ----
    bf16*  src_b  = (bf16*)(ws + 0);         // 13.7 MB
    bf16*  q_b    = (bf16*)(ws + 14 * MB);   // 13.7
    bf16*  val_b  = (bf16*)(ws + 28 * MB);   // 13.7
    float* og     = (float*)(ws + 42 * MB);  // M*480 f32 = 51.2 -> ends 93.2
    bf16*  acc_b  = (bf16*)(ws + 95 * MB);   // 13.7 -> ends 108.7
    bf16*  h_b    = (bf16*)(ws + 0);         // M*2048 bf16 = 109.3 (overlays dead)
    float* y      = (float*)(ws + 110 * MB); // 27.3 (dead after LN1)
    float* z      = (float*)(ws + 110 * MB); // overlays y
    bf16*  x_b    = (bf16*)(ws + 138 * MB);  // 13.7
    float* x_f    = (float*)(ws + 152 * MB); // 27.3 -> ends 179.3
    bf16* wvt    = (bf16*)(ws + 180 * MB);   // 256*256
    bf16* wcat   = wvt + 256 * 256;          // 480*256
    bf16* woutt  = wcat + 480 * 256;         // 256*256
    bf16* w1t    = woutt + 256 * 256;        // 2048*256
    bf16* w2t    = w1t + 2048 * 256;         // 256*2048
    float* bcat  = (float*)(w2t + 256 * 2048); // 480 f32, ends ~182.6 MB
    (void)ws_size; (void)n_in; (void)in_sizes; (void)out_size;

    const int mt = (M + 127) / 128;  // 209

    // ---- fused weight prep (one launch) ----
    prep_kernel<<<1274, 256, 0, stream>>>(wv, wo, wa, wout, w1, w2, bo, ba,
                                          wvt, wcat, woutt, w1t, w2t, bcat);

    // ---- fused activation casts ----
    cast2_kernel<<<(M * C + 255) / 256, 256, 0, stream>>>(src, pos, src_b, q_b, M * C);

    // value = src @ wv + bv  (bf16)
    gemm_mfma<false, true, false><<<dim3(2, mt), 256, 0, stream>>>(
        (const ushort_t*)src_b, (const ushort_t*)wvt, bv, nullptr, val_b, M, 256, 256);

    // og = q @ [wo|wa] + [bo|ba]  (f32, N=480)
    gemm_mfma<false, false, false><<<dim3(4, mt), 256, 0, stream>>>(
        (const ushort_t*)q_b, (const ushort_t*)wcat, bcat, nullptr, og, M, 480, 256);

    // deformable attention -> acc_b (bf16)
    msda_kernel_v2<<<(M + 7) / 8, 256, 0, stream>>>(
        og, refp, (const ushort_t*)val_b, acc_b, M, L);

    // y = acc @ wout + bout + src  (f32)
    gemm_mfma<false, false, true><<<dim3(2, mt), 256, 0, stream>>>(
        (const ushort_t*)acc_b, (const ushort_t*)woutt, bout, src, y, M, 256, 256);

    // x = LN1(y)
    ln_kernel<true><<<M, 256, 0, stream>>>(y, ln1g, ln1b, x_f, x_b);

    // h = relu(x @ w1 + b1)  (bf16)
    gemm_mfma<true, true, false><<<dim3(16, mt), 256, 0, stream>>>(
        (const ushort_t*)x_b, (const ushort_t*)w1t, b1, nullptr, h_b, M, FF, 256);

    // z = h @ w2 + b2 + x  (f32)
    gemm_mfma<false, false, true><<<dim3(2, mt), 256, 0, stream>>>(
        (const ushort_t*)h_b, (const ushort_t*)w2t, b2, x_f, z, M, 256, FF);

    // out = LN2(z)
    ln_kernel<false><<<M, 256, 0, stream>>>(z, ln2g, ln2b, (float*)d_out, nullptr);
}

// Round 7
// 450.438 us; speedup vs baseline: 4.3305x; 1.0272x over previous
//
#include <hip/hip_runtime.h>
#include <hip/hip_bf16.h>

typedef __hip_bfloat16 bf16;
typedef unsigned short ushort_t;
typedef __attribute__((ext_vector_type(8))) short bf16x8;
typedef __attribute__((ext_vector_type(16))) float f32x16;

__device__ __forceinline__ float us2f(unsigned short u) {
    unsigned int x = ((unsigned int)u) << 16;
    return __uint_as_float(x);
}

// async global->LDS, 16 B per lane. LDS dest = wave-uniform base + lane*16.
__device__ __forceinline__ void gl_lds16(const ushort_t* g, ushort_t* l) {
    __builtin_amdgcn_global_load_lds(
        (const __attribute__((address_space(1))) void*)g,
        (__attribute__((address_space(3))) void*)l, 16, 0, 0);
}

// ---------------------------------------------------------------------------
// Fused input cast: src_b = bf16(src), q_b = bf16(src + pos)
// ---------------------------------------------------------------------------
__global__ __launch_bounds__(256) void cast2_kernel(
    const float* __restrict__ src, const float* __restrict__ pos,
    bf16* __restrict__ src_b, bf16* __restrict__ q_b, int n)
{
    int i = blockIdx.x * 256 + threadIdx.x;
    if (i < n) {
        float s = src[i];
        src_b[i] = __float2bfloat16(s);
        q_b[i]   = __float2bfloat16(s + pos[i]);
    }
}

// ---------------------------------------------------------------------------
// Fused weight prep: all transpose-casts + bias concat in ONE launch.
// ---------------------------------------------------------------------------
__global__ __launch_bounds__(256) void prep_kernel(
    const float* __restrict__ wv, const float* __restrict__ wo,
    const float* __restrict__ wa, const float* __restrict__ wout,
    const float* __restrict__ w1, const float* __restrict__ w2,
    const float* __restrict__ bo, const float* __restrict__ ba,
    bf16* __restrict__ wvt, bf16* __restrict__ wcat, bf16* __restrict__ woutt,
    bf16* __restrict__ w1t, bf16* __restrict__ w2t, float* __restrict__ bcat)
{
    __shared__ float tile[32][33];
    const int b = blockIdx.x;
    const float* W; bf16* Wt; int K, N, tb;
    if (b < 64)        { W = wv;   Wt = wvt;            K = 256;  N = 256;  tb = b; }
    else if (b < 144)  { W = wo;   Wt = wcat;           K = 256;  N = 320;  tb = b - 64; }
    else if (b < 184)  { W = wa;   Wt = wcat + 320*256; K = 256;  N = 160;  tb = b - 144; }
    else if (b < 248)  { W = wout; Wt = woutt;          K = 256;  N = 256;  tb = b - 184; }
    else if (b < 760)  { W = w1;   Wt = w1t;            K = 256;  N = 2048; tb = b - 248; }
    else if (b < 1272) { W = w2;   Wt = w2t;            K = 2048; N = 256;  tb = b - 760; }
    else {
        int i = (b - 1272) * 256 + threadIdx.x;
        if (i < 320) bcat[i] = bo[i];
        else if (i < 480) bcat[i] = ba[i - 320];
        return;
    }
    const int ntn = N >> 5;
    const int nb = (tb % ntn) * 32, kb = (tb / ntn) * 32;
    const int tx = threadIdx.x & 31, ty = threadIdx.x >> 5;  // 32 x 8
    #pragma unroll
    for (int i = 0; i < 32; i += 8) {
        int k = kb + ty + i, n = nb + tx;
        tile[ty + i][tx] = (k < K && n < N) ? W[(size_t)k * N + n] : 0.f;
    }
    __syncthreads();
    #pragma unroll
    for (int i = 0; i < 32; i += 8) {
        int n = nb + ty + i, k = kb + tx;
        if (n < N && k < K)
            Wt[(size_t)n * K + k] = __float2bfloat16(tile[tx][ty + i]);
    }
}

// ---------------------------------------------------------------------------
// MFMA bf16 GEMM v2: out[M,N] = A[M,K] @ Bt[N,K]^T + bias (+resid) (relu?)
// 128x128 tile, BK=32, global_load_lds(16B) staging, unpadded LDS (64-B rows),
// 4 waves x (2x2) 32x32x16 MFMA, hoisted incremental staging addresses.
// ---------------------------------------------------------------------------
template<bool RELU, bool OUT_BF16, bool HAS_RESID>
__global__ __launch_bounds__(256, 4) void gemm_mfma(
    const ushort_t* __restrict__ A,    // [M][K] bf16
    const ushort_t* __restrict__ Bt,   // [N][K] bf16
    const float* __restrict__ bias,    // [N] f32
    const float* __restrict__ resid,   // [M][N] f32
    void* __restrict__ outv, int M, int N, int K)
{
    __shared__ ushort_t Asmem[128 * 32];
    __shared__ ushort_t Bsmem[128 * 32];
    const int tid = threadIdx.x;
    const int lane = tid & 63;
    const int wave = tid >> 6;
    const int l32 = lane & 31;
    const int hi  = lane >> 5;
    const int wm = wave >> 1, wn = wave & 1;
    const int m0 = blockIdx.y * 128;
    const int n0 = blockIdx.x * 128;

    const int srow = lane >> 2;
    const int sch  = (lane & 3) * 8;

    const ushort_t* aP[2]; const ushort_t* bP[2];
    ushort_t* aL[2]; ushort_t* bL[2];
    #pragma unroll
    for (int i = 0; i < 2; ++i) {
        const int rbase = wave * 32 + i * 16;
        int mA = m0 + rbase + srow; if (mA > M - 1) mA = M - 1;
        int nB = n0 + rbase + srow; if (nB > N - 1) nB = N - 1;
        aP[i] = A  + (size_t)mA * K + sch;
        bP[i] = Bt + (size_t)nB * K + sch;
        aL[i] = &Asmem[rbase * 32];
        bL[i] = &Bsmem[rbase * 32];
    }

    f32x16 acc[2][2] = {};

    for (int k0 = 0; k0 < K; k0 += 32) {
        #pragma unroll
        for (int i = 0; i < 2; ++i) {
            gl_lds16(aP[i], aL[i]);
            gl_lds16(bP[i], bL[i]);
            aP[i] += 32; bP[i] += 32;
        }
        __syncthreads();

        #pragma unroll
        for (int kw = 0; kw < 2; ++kw) {
            bf16x8 af[2], bfr[2];
            #pragma unroll
            for (int i = 0; i < 2; ++i) {
                const int rowA = wm * 64 + i * 32 + l32;
                af[i] = *reinterpret_cast<const bf16x8*>(
                    &Asmem[rowA * 32 + kw * 16 + hi * 8]);
                const int rowB = wn * 64 + i * 32 + l32;
                bfr[i] = *reinterpret_cast<const bf16x8*>(
                    &Bsmem[rowB * 32 + kw * 16 + hi * 8]);
            }
            #pragma unroll
            for (int i = 0; i < 2; ++i)
                #pragma unroll
                for (int j = 0; j < 2; ++j)
                    acc[i][j] = __builtin_amdgcn_mfma_f32_32x32x16_bf16(
                        af[i], bfr[j], acc[i][j], 0, 0, 0);
        }
        __syncthreads();
    }

    // epilogue: 32x32 C/D layout col = lane&31, row = (r&3) + 8*(r>>2) + 4*hi
    #pragma unroll
    for (int i = 0; i < 2; ++i) {
        const int mb = m0 + wm * 64 + i * 32 + hi * 4;
        #pragma unroll
        for (int j = 0; j < 2; ++j) {
            const int n = n0 + wn * 64 + j * 32 + l32;
            if (n >= N) continue;
            const float bval = bias[n];
            #pragma unroll
            for (int r = 0; r < 16; ++r) {
                const int m = mb + (r & 3) + (r >> 2) * 8;
                if (m >= M) continue;
                float v = acc[i][j][r] + bval;
                if (HAS_RESID) v += resid[(size_t)m * N + n];
                if (RELU) v = fmaxf(v, 0.f);
                if (OUT_BF16)
                    ((bf16*)outv)[(size_t)m * N + n] = __float2bfloat16(v);
                else
                    ((float*)outv)[(size_t)m * N + n] = v;
            }
        }
    }
}

// ---------------------------------------------------------------------------
// MS-deformable attention v3: phase-A tuple setup + phase-B pure gather-FMA.
// Block = 8 queries x 32 threads. Per (q,h,point) tuple, phase A precomputes
// two clamped row byte-offsets + 4 slot weights (attention and validity
// folded in, exact column-pair remap). Phase B: per lane (h, 8-ch group):
// 2 broadcast LDS reads + 4 unconditional 16-B gathers + 32 unpack/FMA.
// ---------------------------------------------------------------------------
__global__ __launch_bounds__(256) void msda_kernel_v3(
    const float* __restrict__ og,        // [M,480]: offs 0..319, logits 320..479
    const float* __restrict__ refp,      // [M,10]
    const ushort_t* __restrict__ value,  // [M,256] bf16 = (B,L,H,32)
    bf16* __restrict__ out,              // [M,256] bf16
    int M, int L)
{
    const int tid = threadIdx.x;
    const int qbase = blockIdx.x * 8;

    __shared__ float  s_attn[8][160];
    __shared__ int2   s_off[1280];       // (row0, row1) byte offsets
    __shared__ float4 s_w[1280];         // slot weights (c0r0, c1r0, c0r1, c1r1)
    __shared__ int    s_Wl[5], s_St[5];

    if (tid < 5) {
        const int HW[5] = {100, 50, 25, 13, 7};
        const int st[5] = {0, 10000, 12500, 13125, 13294};
        s_Wl[tid] = HW[tid];
        s_St[tid] = st[tid];
    }

    // stage logits
    for (int i = tid; i < 1280; i += 256) {
        int q = i / 160, j = i - q * 160;
        int qq = qbase + q;
        s_attn[q][j] = (qq < M) ? og[(size_t)qq * 480 + 320 + j] : 0.f;
    }
    __syncthreads();

    // softmax: thread t<64 handles (query t>>3, head t&7)
    if (tid < 64) {
        float* a = &s_attn[tid >> 3][(tid & 7) * 20];
        float mx = -1e30f;
        #pragma unroll
        for (int i = 0; i < 20; ++i) mx = fmaxf(mx, a[i]);
        float ssum = 0.f;
        #pragma unroll
        for (int i = 0; i < 20; ++i) {
            float e = __expf(a[i] - mx);
            a[i] = e;
            ssum += e;
        }
        float inv = 1.f / ssum;
        #pragma unroll
        for (int i = 0; i < 20; ++i) a[i] *= inv;
    }
    __syncthreads();

    // phase A: 1280 tuples, 5 per thread
    #pragma unroll
    for (int it = 0; it < 5; ++it) {
        const int t = tid + it * 256;
        const int q  = t / 160;
        const int r  = t - q * 160;        // h*20 + l*4 + pt
        const int h  = r / 20;
        const int p20 = r - h * 20;
        const int l  = p20 >> 2;
        const int qq = qbase + q;

        int2 offp = {0, 0};
        float4 wp = {0.f, 0.f, 0.f, 0.f};
        if (qq < M) {
            const int Wi = s_Wl[l];
            const int s0 = s_St[l];
            const float Wf = (float)Wi;
            const float2 o2 = *reinterpret_cast<const float2*>(
                &og[(size_t)qq * 480 + r * 2]);
            const float2 rf = *reinterpret_cast<const float2*>(
                &refp[(size_t)qq * 10 + l * 2]);
            const float a = s_attn[q][r];

            const float px = fmaf(rf.x, Wf, -0.5f) + o2.x;
            const float py = fmaf(rf.y, Wf, -0.5f) + o2.y;
            const float x0f = floorf(px);
            const float y0f = floorf(py);
            const float lx = px - x0f;
            const float ly = py - y0f;
            const int x0 = (int)x0f;
            const int y0 = (int)y0f;

            // validity-folded corner weights
            const float wx0v = (x0 >= 0 && x0 < Wi) ? (1.f - lx) : 0.f;
            const float wx1v = (x0 + 1 >= 0 && x0 + 1 < Wi) ? lx : 0.f;
            const float wy0v = (y0 >= 0 && y0 < Wi) ? (1.f - ly) : 0.f;
            const float wy1v = (y0 + 1 >= 0 && y0 + 1 < Wi) ? ly : 0.f;

            // clamped slot columns/rows; remap logical corners to slots
            const int c0 = min(max(x0, 0), Wi - 2);
            const int r0 = min(max(y0, 0), Wi - 2);
            const float swx0 = (x0 == c0 ? wx0v : 0.f) + (x0 + 1 == c0 ? wx1v : 0.f);
            const float swx1 = (x0 == c0 + 1 ? wx0v : 0.f) + (x0 + 1 == c0 + 1 ? wx1v : 0.f);
            const float swy0 = (y0 == r0 ? wy0v : 0.f) + (y0 + 1 == r0 ? wy1v : 0.f);
            const float swy1 = (y0 == r0 + 1 ? wy0v : 0.f) + (y0 + 1 == r0 + 1 ? wy1v : 0.f);

            offp.x = (s0 + r0 * Wi + c0) * 512;   // byte offset of row r0 slot
            offp.y = offp.x + Wi * 512;           // row r1
            wp.x = a * swx0 * swy0;
            wp.y = a * swx1 * swy0;
            wp.z = a * swx0 * swy1;
            wp.w = a * swx1 * swy1;
        }
        s_off[t] = offp;
        s_w[t] = wp;
    }
    __syncthreads();

    // phase B
    const int qi  = tid >> 5;
    const int g   = tid & 31;
    const int h   = g >> 2;
    const int sub = g & 3;
    const int bq = qbase + qi;
    if (bq >= M) return;
    const int b = bq / L;

    const char* vb = (const char*)value + (size_t)b * L * 512 + h * 64 + sub * 16;

    float acc[8] = {};
    const int tb = qi * 160 + h * 20;
    #pragma unroll 2
    for (int p = 0; p < 20; ++p) {
        const int2 off = s_off[tb + p];
        const float4 w = s_w[tb + p];
        const int4 u00 = *reinterpret_cast<const int4*>(vb + off.x);
        const int4 u10 = *reinterpret_cast<const int4*>(vb + off.x + 512);
        const int4 u01 = *reinterpret_cast<const int4*>(vb + off.y);
        const int4 u11 = *reinterpret_cast<const int4*>(vb + off.y + 512);
        #define ACC4(u, wt)                                                        \
            acc[0] = fmaf(wt, __uint_as_float((unsigned)(u).x << 16), acc[0]);      \
            acc[1] = fmaf(wt, __uint_as_float((unsigned)(u).x & 0xffff0000u), acc[1]); \
            acc[2] = fmaf(wt, __uint_as_float((unsigned)(u).y << 16), acc[2]);      \
            acc[3] = fmaf(wt, __uint_as_float((unsigned)(u).y & 0xffff0000u), acc[3]); \
            acc[4] = fmaf(wt, __uint_as_float((unsigned)(u).z << 16), acc[4]);      \
            acc[5] = fmaf(wt, __uint_as_float((unsigned)(u).z & 0xffff0000u), acc[5]); \
            acc[6] = fmaf(wt, __uint_as_float((unsigned)(u).w << 16), acc[6]);      \
            acc[7] = fmaf(wt, __uint_as_float((unsigned)(u).w & 0xffff0000u), acc[7]);
        ACC4(u00, w.x)
        ACC4(u10, w.y)
        ACC4(u01, w.z)
        ACC4(u11, w.w)
        #undef ACC4
    }

    ushort_t o[8];
    #pragma unroll
    for (int i = 0; i < 8; ++i)
        o[i] = ((__hip_bfloat16_raw)__float2bfloat16(acc[i])).x;
    int4 pkt;
    pkt.x = (int)o[0] | ((int)o[1] << 16);
    pkt.y = (int)o[2] | ((int)o[3] << 16);
    pkt.z = (int)o[4] | ((int)o[5] << 16);
    pkt.w = (int)o[6] | ((int)o[7] << 16);
    *reinterpret_cast<int4*>((ushort_t*)out + (size_t)bq * 256 + h * 32 + sub * 8) = pkt;
}

// ---------------------------------------------------------------------------
template<bool DUAL>
__global__ __launch_bounds__(256) void ln_kernel(
    const float* __restrict__ y, const float* __restrict__ g,
    const float* __restrict__ bta, float* __restrict__ outf,
    bf16* __restrict__ outb)
{
    const int row = blockIdx.x;
    const int tid = threadIdx.x;
    float v = y[(size_t)row * 256 + tid];
    float s = v, ss = v * v;
    #pragma unroll
    for (int o = 32; o > 0; o >>= 1) {
        s += __shfl_down(s, o);
        ss += __shfl_down(ss, o);
    }
    __shared__ float red[8];
    const int wid = tid >> 6, lane = tid & 63;
    if (lane == 0) { red[wid] = s; red[4 + wid] = ss; }
    __syncthreads();
    const float S = red[0] + red[1] + red[2] + red[3];
    const float SS = red[4] + red[5] + red[6] + red[7];
    const float mean = S * (1.f / 256.f);
    const float var = SS * (1.f / 256.f) - mean * mean;
    const float rs = rsqrtf(var + 1e-5f);
    const float o = (v - mean) * rs * g[tid] + bta[tid];
    outf[(size_t)row * 256 + tid] = o;
    if (DUAL) outb[(size_t)row * 256 + tid] = __float2bfloat16(o);
}

// ---------------------------------------------------------------------------
extern "C" void kernel_launch(void* const* d_in, const int* in_sizes, int n_in,
                              void* d_out, int out_size, void* d_ws, size_t ws_size,
                              hipStream_t stream)
{
    const int B = 2, L = 13343, C = 256, FF = 2048;
    const int M = B * L;  // 26686

    const float* src  = (const float*)d_in[0];
    const float* pos  = (const float*)d_in[1];
    const float* refp = (const float*)d_in[2];
    const float* wv   = (const float*)d_in[3];
    const float* bv   = (const float*)d_in[4];
    const float* wo   = (const float*)d_in[5];
    const float* bo   = (const float*)d_in[6];
    const float* wa   = (const float*)d_in[7];
    const float* ba   = (const float*)d_in[8];
    const float* wout = (const float*)d_in[9];
    const float* bout = (const float*)d_in[10];
    const float* ln1g = (const float*)d_in[11];
    const float* ln1b = (const float*)d_in[12];
    const float* w1   = (const float*)d_in[13];
    const float* b1   = (const float*)d_in[14];
    const float* w2   = (const float*)d_in[15];
    const float* b2   = (const float*)d_in[16];
    const float* ln2g = (const float*)d_in[17];
    const float* ln2b = (const float*)d_in[18];

    char* ws = (char*)d_ws;
    const size_t MB = 1ull << 20;
    // ---- workspace overlay (peak ~184 MB) ----
    bf16*  src_b  = (bf16*)(ws + 0);         // 13.7 MB
    bf16*  q_b    = (bf16*)(ws + 14 * MB);   // 13.7
    bf16*  val_b  = (bf16*)(ws + 28 * MB);   // 13.7
    float* og     = (float*)(ws + 42 * MB);  // M*480 f32 = 51.2 -> ends 93.2
    bf16*  acc_b  = (bf16*)(ws + 95 * MB);   // 13.7 -> ends 108.7
    bf16*  h_b    = (bf16*)(ws + 0);         // M*2048 bf16 = 109.3 (overlays dead)
    float* y      = (float*)(ws + 110 * MB); // 27.3 (dead after LN1)
    float* z      = (float*)(ws + 110 * MB); // overlays y
    bf16*  x_b    = (bf16*)(ws + 138 * MB);  // 13.7
    float* x_f    = (float*)(ws + 152 * MB); // 27.3 -> ends 179.3
    bf16* wvt    = (bf16*)(ws + 180 * MB);   // 256*256
    bf16* wcat   = wvt + 256 * 256;          // 480*256
    bf16* woutt  = wcat + 480 * 256;         // 256*256
    bf16* w1t    = woutt + 256 * 256;        // 2048*256
    bf16* w2t    = w1t + 2048 * 256;         // 256*2048
    float* bcat  = (float*)(w2t + 256 * 2048); // 480 f32, ends ~182.6 MB
    (void)ws_size; (void)n_in; (void)in_sizes; (void)out_size;

    const int mt = (M + 127) / 128;  // 209

    // ---- fused weight prep (one launch) ----
    prep_kernel<<<1274, 256, 0, stream>>>(wv, wo, wa, wout, w1, w2, bo, ba,
                                          wvt, wcat, woutt, w1t, w2t, bcat);

    // ---- fused activation casts ----
    cast2_kernel<<<(M * C + 255) / 256, 256, 0, stream>>>(src, pos, src_b, q_b, M * C);

    // value = src @ wv + bv  (bf16)
    gemm_mfma<false, true, false><<<dim3(2, mt), 256, 0, stream>>>(
        (const ushort_t*)src_b, (const ushort_t*)wvt, bv, nullptr, val_b, M, 256, 256);

    // og = q @ [wo|wa] + [bo|ba]  (f32, N=480)
    gemm_mfma<false, false, false><<<dim3(4, mt), 256, 0, stream>>>(
        (const ushort_t*)q_b, (const ushort_t*)wcat, bcat, nullptr, og, M, 480, 256);

    // deformable attention -> acc_b (bf16)
    msda_kernel_v3<<<(M + 7) / 8, 256, 0, stream>>>(
        og, refp, (const ushort_t*)val_b, acc_b, M, L);

    // y = acc @ wout + bout + src  (f32)
    gemm_mfma<false, false, true><<<dim3(2, mt), 256, 0, stream>>>(
        (const ushort_t*)acc_b, (const ushort_t*)woutt, bout, src, y, M, 256, 256);

    // x = LN1(y)
    ln_kernel<true><<<M, 256, 0, stream>>>(y, ln1g, ln1b, x_f, x_b);

    // h = relu(x @ w1 + b1)  (bf16)
    gemm_mfma<true, true, false><<<dim3(16, mt), 256, 0, stream>>>(
        (const ushort_t*)x_b, (const ushort_t*)w1t, b1, nullptr, h_b, M, FF, 256);

    // z = h @ w2 + b2 + x  (f32)
    gemm_mfma<false, false, true><<<dim3(2, mt), 256, 0, stream>>>(
        (const ushort_t*)h_b, (const ushort_t*)w2t, b2, x_f, z, M, 256, FF);

    // out = LN2(z)
    ln_kernel<false><<<M, 256, 0, stream>>>(z, ln2g, ln2b, (float*)d_out, nullptr);
}

// Round 8
// 449.440 us; speedup vs baseline: 4.3402x; 1.0022x over previous
//
#include <hip/hip_runtime.h>
#include <hip/hip_bf16.h>

typedef __hip_bfloat16 bf16;
typedef unsigned short ushort_t;
typedef __attribute__((ext_vector_type(8))) short bf16x8;
typedef __attribute__((ext_vector_type(16))) float f32x16;

__device__ __forceinline__ float us2f(unsigned short u) {
    unsigned int x = ((unsigned int)u) << 16;
    return __uint_as_float(x);
}

// async global->LDS, 16 B per lane. LDS dest = wave-uniform base + lane*16.
__device__ __forceinline__ void gl_lds16(const ushort_t* g, ushort_t* l) {
    __builtin_amdgcn_global_load_lds(
        (const __attribute__((address_space(1))) void*)g,
        (__attribute__((address_space(3))) void*)l, 16, 0, 0);
}

// ---------------------------------------------------------------------------
// Fused input cast: src_b = bf16(src), q_b = bf16(src + pos)
// ---------------------------------------------------------------------------
__global__ __launch_bounds__(256) void cast2_kernel(
    const float* __restrict__ src, const float* __restrict__ pos,
    bf16* __restrict__ src_b, bf16* __restrict__ q_b, int n)
{
    int i = blockIdx.x * 256 + threadIdx.x;
    if (i < n) {
        float s = src[i];
        src_b[i] = __float2bfloat16(s);
        q_b[i]   = __float2bfloat16(s + pos[i]);
    }
}

// ---------------------------------------------------------------------------
// Fused weight prep: all transpose-casts + bias concat in ONE launch.
// ---------------------------------------------------------------------------
__global__ __launch_bounds__(256) void prep_kernel(
    const float* __restrict__ wv, const float* __restrict__ wo,
    const float* __restrict__ wa, const float* __restrict__ wout,
    const float* __restrict__ w1, const float* __restrict__ w2,
    const float* __restrict__ bo, const float* __restrict__ ba,
    bf16* __restrict__ wvt, bf16* __restrict__ wcat, bf16* __restrict__ woutt,
    bf16* __restrict__ w1t, bf16* __restrict__ w2t, float* __restrict__ bcat)
{
    __shared__ float tile[32][33];
    const int b = blockIdx.x;
    const float* W; bf16* Wt; int K, N, tb;
    if (b < 64)        { W = wv;   Wt = wvt;            K = 256;  N = 256;  tb = b; }
    else if (b < 144)  { W = wo;   Wt = wcat;           K = 256;  N = 320;  tb = b - 64; }
    else if (b < 184)  { W = wa;   Wt = wcat + 320*256; K = 256;  N = 160;  tb = b - 144; }
    else if (b < 248)  { W = wout; Wt = woutt;          K = 256;  N = 256;  tb = b - 184; }
    else if (b < 760)  { W = w1;   Wt = w1t;            K = 256;  N = 2048; tb = b - 248; }
    else if (b < 1272) { W = w2;   Wt = w2t;            K = 2048; N = 256;  tb = b - 760; }
    else {
        int i = (b - 1272) * 256 + threadIdx.x;
        if (i < 320) bcat[i] = bo[i];
        else if (i < 480) bcat[i] = ba[i - 320];
        return;
    }
    const int ntn = N >> 5;
    const int nb = (tb % ntn) * 32, kb = (tb / ntn) * 32;
    const int tx = threadIdx.x & 31, ty = threadIdx.x >> 5;  // 32 x 8
    #pragma unroll
    for (int i = 0; i < 32; i += 8) {
        int k = kb + ty + i, n = nb + tx;
        tile[ty + i][tx] = (k < K && n < N) ? W[(size_t)k * N + n] : 0.f;
    }
    __syncthreads();
    #pragma unroll
    for (int i = 0; i < 32; i += 8) {
        int n = nb + ty + i, k = kb + tx;
        if (n < N && k < K)
            Wt[(size_t)n * K + k] = __float2bfloat16(tile[tx][ty + i]);
    }
}

// ---------------------------------------------------------------------------
// MFMA bf16 GEMM (128x128 tile): for large-N GEMMs (og N=480, FFN1 N=2048).
// ---------------------------------------------------------------------------
template<bool RELU, bool OUT_BF16, bool HAS_RESID>
__global__ __launch_bounds__(256, 4) void gemm_mfma(
    const ushort_t* __restrict__ A,    // [M][K] bf16
    const ushort_t* __restrict__ Bt,   // [N][K] bf16
    const float* __restrict__ bias,    // [N] f32
    const float* __restrict__ resid,   // [M][N] f32
    void* __restrict__ outv, int M, int N, int K)
{
    __shared__ ushort_t Asmem[128 * 32];
    __shared__ ushort_t Bsmem[128 * 32];
    const int tid = threadIdx.x;
    const int lane = tid & 63;
    const int wave = tid >> 6;
    const int l32 = lane & 31;
    const int hi  = lane >> 5;
    const int wm = wave >> 1, wn = wave & 1;
    const int m0 = blockIdx.y * 128;
    const int n0 = blockIdx.x * 128;

    const int srow = lane >> 2;
    const int sch  = (lane & 3) * 8;

    const ushort_t* aP[2]; const ushort_t* bP[2];
    ushort_t* aL[2]; ushort_t* bL[2];
    #pragma unroll
    for (int i = 0; i < 2; ++i) {
        const int rbase = wave * 32 + i * 16;
        int mA = m0 + rbase + srow; if (mA > M - 1) mA = M - 1;
        int nB = n0 + rbase + srow; if (nB > N - 1) nB = N - 1;
        aP[i] = A  + (size_t)mA * K + sch;
        bP[i] = Bt + (size_t)nB * K + sch;
        aL[i] = &Asmem[rbase * 32];
        bL[i] = &Bsmem[rbase * 32];
    }

    f32x16 acc[2][2] = {};

    for (int k0 = 0; k0 < K; k0 += 32) {
        #pragma unroll
        for (int i = 0; i < 2; ++i) {
            gl_lds16(aP[i], aL[i]);
            gl_lds16(bP[i], bL[i]);
            aP[i] += 32; bP[i] += 32;
        }
        __syncthreads();

        #pragma unroll
        for (int kw = 0; kw < 2; ++kw) {
            bf16x8 af[2], bfr[2];
            #pragma unroll
            for (int i = 0; i < 2; ++i) {
                const int rowA = wm * 64 + i * 32 + l32;
                af[i] = *reinterpret_cast<const bf16x8*>(
                    &Asmem[rowA * 32 + kw * 16 + hi * 8]);
                const int rowB = wn * 64 + i * 32 + l32;
                bfr[i] = *reinterpret_cast<const bf16x8*>(
                    &Bsmem[rowB * 32 + kw * 16 + hi * 8]);
            }
            #pragma unroll
            for (int i = 0; i < 2; ++i)
                #pragma unroll
                for (int j = 0; j < 2; ++j)
                    acc[i][j] = __builtin_amdgcn_mfma_f32_32x32x16_bf16(
                        af[i], bfr[j], acc[i][j], 0, 0, 0);
        }
        __syncthreads();
    }

    // epilogue: 32x32 C/D layout col = lane&31, row = (r&3) + 8*(r>>2) + 4*hi
    #pragma unroll
    for (int i = 0; i < 2; ++i) {
        const int mb = m0 + wm * 64 + i * 32 + hi * 4;
        #pragma unroll
        for (int j = 0; j < 2; ++j) {
            const int n = n0 + wn * 64 + j * 32 + l32;
            if (n >= N) continue;
            const float bval = bias[n];
            #pragma unroll
            for (int r = 0; r < 16; ++r) {
                const int m = mb + (r & 3) + (r >> 2) * 8;
                if (m >= M) continue;
                float v = acc[i][j][r] + bval;
                if (HAS_RESID) v += resid[(size_t)m * N + n];
                if (RELU) v = fmaxf(v, 0.f);
                if (OUT_BF16)
                    ((bf16*)outv)[(size_t)m * N + n] = __float2bfloat16(v);
                else
                    ((float*)outv)[(size_t)m * N + n] = v;
            }
        }
    }
}

// ---------------------------------------------------------------------------
// MFMA bf16 GEMM (128x64 tile): for N=256 GEMMs (value, wout, FFN2).
// 2x more blocks than 128x128 -> fixes grid starvation (R7: Occupancy 17%).
// 4 waves, each 32 rows x 64 cols = 1x2 32x32x16 MFMA, 32 AGPRs, 12 KB LDS.
// ---------------------------------------------------------------------------
template<bool RELU, bool OUT_BF16, bool HAS_RESID>
__global__ __launch_bounds__(256, 4) void gemm_mfma64(
    const ushort_t* __restrict__ A,    // [M][K] bf16
    const ushort_t* __restrict__ Bt,   // [N][K] bf16
    const float* __restrict__ bias,    // [N] f32
    const float* __restrict__ resid,   // [M][N] f32
    void* __restrict__ outv, int M, int N, int K)
{
    __shared__ ushort_t Asmem[128 * 32];
    __shared__ ushort_t Bsmem[64 * 32];
    const int tid = threadIdx.x;
    const int lane = tid & 63;
    const int wave = tid >> 6;
    const int l32 = lane & 31;
    const int hi  = lane >> 5;
    const int m0 = blockIdx.y * 128;
    const int n0 = blockIdx.x * 64;

    const int srow = lane >> 2;       // 0..15
    const int sch  = (lane & 3) * 8;

    // A: wave stages rows wave*32 .. wave*32+31 (2 calls); B: rows wave*16.. (1 call)
    const ushort_t* aP[2]; ushort_t* aL[2];
    #pragma unroll
    for (int i = 0; i < 2; ++i) {
        const int rbase = wave * 32 + i * 16;
        int mA = m0 + rbase + srow; if (mA > M - 1) mA = M - 1;
        aP[i] = A + (size_t)mA * K + sch;
        aL[i] = &Asmem[rbase * 32];
    }
    const int brbase = wave * 16;
    int nB = n0 + brbase + srow; if (nB > N - 1) nB = N - 1;
    const ushort_t* bP = Bt + (size_t)nB * K + sch;
    ushort_t* bL = &Bsmem[brbase * 32];

    f32x16 acc[2] = {};

    for (int k0 = 0; k0 < K; k0 += 32) {
        gl_lds16(aP[0], aL[0]); aP[0] += 32;
        gl_lds16(aP[1], aL[1]); aP[1] += 32;
        gl_lds16(bP, bL);       bP    += 32;
        __syncthreads();

        #pragma unroll
        for (int kw = 0; kw < 2; ++kw) {
            const int rowA = wave * 32 + l32;
            const bf16x8 af = *reinterpret_cast<const bf16x8*>(
                &Asmem[rowA * 32 + kw * 16 + hi * 8]);
            bf16x8 bfr[2];
            #pragma unroll
            for (int j = 0; j < 2; ++j) {
                const int rowB = j * 32 + l32;
                bfr[j] = *reinterpret_cast<const bf16x8*>(
                    &Bsmem[rowB * 32 + kw * 16 + hi * 8]);
            }
            #pragma unroll
            for (int j = 0; j < 2; ++j)
                acc[j] = __builtin_amdgcn_mfma_f32_32x32x16_bf16(
                    af, bfr[j], acc[j], 0, 0, 0);
        }
        __syncthreads();
    }

    // epilogue: wave owns rows m0+wave*32 .. +31, cols n0 .. n0+63
    #pragma unroll
    for (int j = 0; j < 2; ++j) {
        const int n = n0 + j * 32 + l32;
        if (n >= N) continue;
        const float bval = bias[n];
        const int mb = m0 + wave * 32 + hi * 4;
        #pragma unroll
        for (int r = 0; r < 16; ++r) {
            const int m = mb + (r & 3) + (r >> 2) * 8;
            if (m >= M) continue;
            float v = acc[j][r] + bval;
            if (HAS_RESID) v += resid[(size_t)m * N + n];
            if (RELU) v = fmaxf(v, 0.f);
            if (OUT_BF16)
                ((bf16*)outv)[(size_t)m * N + n] = __float2bfloat16(v);
            else
                ((float*)outv)[(size_t)m * N + n] = v;
        }
    }
}

// ---------------------------------------------------------------------------
// MS-deformable attention v3: phase-A tuple setup + phase-B pure gather-FMA.
// ---------------------------------------------------------------------------
__global__ __launch_bounds__(256) void msda_kernel_v3(
    const float* __restrict__ og,        // [M,480]: offs 0..319, logits 320..479
    const float* __restrict__ refp,      // [M,10]
    const ushort_t* __restrict__ value,  // [M,256] bf16 = (B,L,H,32)
    bf16* __restrict__ out,              // [M,256] bf16
    int M, int L)
{
    const int tid = threadIdx.x;
    const int qbase = blockIdx.x * 8;

    __shared__ float  s_attn[8][160];
    __shared__ int2   s_off[1280];
    __shared__ float4 s_w[1280];
    __shared__ int    s_Wl[5], s_St[5];

    if (tid < 5) {
        const int HW[5] = {100, 50, 25, 13, 7};
        const int st[5] = {0, 10000, 12500, 13125, 13294};
        s_Wl[tid] = HW[tid];
        s_St[tid] = st[tid];
    }

    for (int i = tid; i < 1280; i += 256) {
        int q = i / 160, j = i - q * 160;
        int qq = qbase + q;
        s_attn[q][j] = (qq < M) ? og[(size_t)qq * 480 + 320 + j] : 0.f;
    }
    __syncthreads();

    if (tid < 64) {
        float* a = &s_attn[tid >> 3][(tid & 7) * 20];
        float mx = -1e30f;
        #pragma unroll
        for (int i = 0; i < 20; ++i) mx = fmaxf(mx, a[i]);
        float ssum = 0.f;
        #pragma unroll
        for (int i = 0; i < 20; ++i) {
            float e = __expf(a[i] - mx);
            a[i] = e;
            ssum += e;
        }
        float inv = 1.f / ssum;
        #pragma unroll
        for (int i = 0; i < 20; ++i) a[i] *= inv;
    }
    __syncthreads();

    #pragma unroll
    for (int it = 0; it < 5; ++it) {
        const int t = tid + it * 256;
        const int q  = t / 160;
        const int r  = t - q * 160;
        const int l  = (r - (r / 20) * 20) >> 2;
        const int qq = qbase + q;

        int2 offp = {0, 0};
        float4 wp = {0.f, 0.f, 0.f, 0.f};
        if (qq < M) {
            const int Wi = s_Wl[l];
            const int s0 = s_St[l];
            const float Wf = (float)Wi;
            const float2 o2 = *reinterpret_cast<const float2*>(
                &og[(size_t)qq * 480 + r * 2]);
            const float2 rf = *reinterpret_cast<const float2*>(
                &refp[(size_t)qq * 10 + l * 2]);
            const float a = s_attn[q][r];

            const float px = fmaf(rf.x, Wf, -0.5f) + o2.x;
            const float py = fmaf(rf.y, Wf, -0.5f) + o2.y;
            const float x0f = floorf(px);
            const float y0f = floorf(py);
            const float lx = px - x0f;
            const float ly = py - y0f;
            const int x0 = (int)x0f;
            const int y0 = (int)y0f;

            const float wx0v = (x0 >= 0 && x0 < Wi) ? (1.f - lx) : 0.f;
            const float wx1v = (x0 + 1 >= 0 && x0 + 1 < Wi) ? lx : 0.f;
            const float wy0v = (y0 >= 0 && y0 < Wi) ? (1.f - ly) : 0.f;
            const float wy1v = (y0 + 1 >= 0 && y0 + 1 < Wi) ? ly : 0.f;

            const int c0 = min(max(x0, 0), Wi - 2);
            const int r0 = min(max(y0, 0), Wi - 2);
            const float swx0 = (x0 == c0 ? wx0v : 0.f) + (x0 + 1 == c0 ? wx1v : 0.f);
            const float swx1 = (x0 == c0 + 1 ? wx0v : 0.f) + (x0 + 1 == c0 + 1 ? wx1v : 0.f);
            const float swy0 = (y0 == r0 ? wy0v : 0.f) + (y0 + 1 == r0 ? wy1v : 0.f);
            const float swy1 = (y0 == r0 + 1 ? wy0v : 0.f) + (y0 + 1 == r0 + 1 ? wy1v : 0.f);

            offp.x = (s0 + r0 * Wi + c0) * 512;
            offp.y = offp.x + Wi * 512;
            wp.x = a * swx0 * swy0;
            wp.y = a * swx1 * swy0;
            wp.z = a * swx0 * swy1;
            wp.w = a * swx1 * swy1;
        }
        s_off[t] = offp;
        s_w[t] = wp;
    }
    __syncthreads();

    const int qi  = tid >> 5;
    const int g   = tid & 31;
    const int h   = g >> 2;
    const int sub = g & 3;
    const int bq = qbase + qi;
    if (bq >= M) return;
    const int b = bq / L;

    const char* vb = (const char*)value + (size_t)b * L * 512 + h * 64 + sub * 16;

    float acc[8] = {};
    const int tb = qi * 160 + h * 20;
    #pragma unroll 2
    for (int p = 0; p < 20; ++p) {
        const int2 off = s_off[tb + p];
        const float4 w = s_w[tb + p];
        const int4 u00 = *reinterpret_cast<const int4*>(vb + off.x);
        const int4 u10 = *reinterpret_cast<const int4*>(vb + off.x + 512);
        const int4 u01 = *reinterpret_cast<const int4*>(vb + off.y);
        const int4 u11 = *reinterpret_cast<const int4*>(vb + off.y + 512);
        #define ACC4(u, wt)                                                        \
            acc[0] = fmaf(wt, __uint_as_float((unsigned)(u).x << 16), acc[0]);      \
            acc[1] = fmaf(wt, __uint_as_float((unsigned)(u).x & 0xffff0000u), acc[1]); \
            acc[2] = fmaf(wt, __uint_as_float((unsigned)(u).y << 16), acc[2]);      \
            acc[3] = fmaf(wt, __uint_as_float((unsigned)(u).y & 0xffff0000u), acc[3]); \
            acc[4] = fmaf(wt, __uint_as_float((unsigned)(u).z << 16), acc[4]);      \
            acc[5] = fmaf(wt, __uint_as_float((unsigned)(u).z & 0xffff0000u), acc[5]); \
            acc[6] = fmaf(wt, __uint_as_float((unsigned)(u).w << 16), acc[6]);      \
            acc[7] = fmaf(wt, __uint_as_float((unsigned)(u).w & 0xffff0000u), acc[7]);
        ACC4(u00, w.x)
        ACC4(u10, w.y)
        ACC4(u01, w.z)
        ACC4(u11, w.w)
        #undef ACC4
    }

    ushort_t o[8];
    #pragma unroll
    for (int i = 0; i < 8; ++i)
        o[i] = ((__hip_bfloat16_raw)__float2bfloat16(acc[i])).x;
    int4 pkt;
    pkt.x = (int)o[0] | ((int)o[1] << 16);
    pkt.y = (int)o[2] | ((int)o[3] << 16);
    pkt.z = (int)o[4] | ((int)o[5] << 16);
    pkt.w = (int)o[6] | ((int)o[7] << 16);
    *reinterpret_cast<int4*>((ushort_t*)out + (size_t)bq * 256 + h * 32 + sub * 8) = pkt;
}

// ---------------------------------------------------------------------------
template<bool DUAL>
__global__ __launch_bounds__(256) void ln_kernel(
    const float* __restrict__ y, const float* __restrict__ g,
    const float* __restrict__ bta, float* __restrict__ outf,
    bf16* __restrict__ outb)
{
    const int row = blockIdx.x;
    const int tid = threadIdx.x;
    float v = y[(size_t)row * 256 + tid];
    float s = v, ss = v * v;
    #pragma unroll
    for (int o = 32; o > 0; o >>= 1) {
        s += __shfl_down(s, o);
        ss += __shfl_down(ss, o);
    }
    __shared__ float red[8];
    const int wid = tid >> 6, lane = tid & 63;
    if (lane == 0) { red[wid] = s; red[4 + wid] = ss; }
    __syncthreads();
    const float S = red[0] + red[1] + red[2] + red[3];
    const float SS = red[4] + red[5] + red[6] + red[7];
    const float mean = S * (1.f / 256.f);
    const float var = SS * (1.f / 256.f) - mean * mean;
    const float rs = rsqrtf(var + 1e-5f);
    const float o = (v - mean) * rs * g[tid] + bta[tid];
    outf[(size_t)row * 256 + tid] = o;
    if (DUAL) outb[(size_t)row * 256 + tid] = __float2bfloat16(o);
}

// ---------------------------------------------------------------------------
extern "C" void kernel_launch(void* const* d_in, const int* in_sizes, int n_in,
                              void* d_out, int out_size, void* d_ws, size_t ws_size,
                              hipStream_t stream)
{
    const int B = 2, L = 13343, C = 256, FF = 2048;
    const int M = B * L;  // 26686

    const float* src  = (const float*)d_in[0];
    const float* pos  = (const float*)d_in[1];
    const float* refp = (const float*)d_in[2];
    const float* wv   = (const float*)d_in[3];
    const float* bv   = (const float*)d_in[4];
    const float* wo   = (const float*)d_in[5];
    const float* bo   = (const float*)d_in[6];
    const float* wa   = (const float*)d_in[7];
    const float* ba   = (const float*)d_in[8];
    const float* wout = (const float*)d_in[9];
    const float* bout = (const float*)d_in[10];
    const float* ln1g = (const float*)d_in[11];
    const float* ln1b = (const float*)d_in[12];
    const float* w1   = (const float*)d_in[13];
    const float* b1   = (const float*)d_in[14];
    const float* w2   = (const float*)d_in[15];
    const float* b2   = (const float*)d_in[16];
    const float* ln2g = (const float*)d_in[17];
    const float* ln2b = (const float*)d_in[18];

    char* ws = (char*)d_ws;
    const size_t MB = 1ull << 20;
    // ---- workspace overlay (peak ~184 MB) ----
    bf16*  src_b  = (bf16*)(ws + 0);         // 13.7 MB
    bf16*  q_b    = (bf16*)(ws + 14 * MB);   // 13.7
    bf16*  val_b  = (bf16*)(ws + 28 * MB);   // 13.7
    float* og     = (float*)(ws + 42 * MB);  // M*480 f32 = 51.2 -> ends 93.2
    bf16*  acc_b  = (bf16*)(ws + 95 * MB);   // 13.7 -> ends 108.7
    bf16*  h_b    = (bf16*)(ws + 0);         // M*2048 bf16 = 109.3 (overlays dead)
    float* y      = (float*)(ws + 110 * MB); // 27.3 (dead after LN1)
    float* z      = (float*)(ws + 110 * MB); // overlays y
    bf16*  x_b    = (bf16*)(ws + 138 * MB);  // 13.7
    float* x_f    = (float*)(ws + 152 * MB); // 27.3 -> ends 179.3
    bf16* wvt    = (bf16*)(ws + 180 * MB);   // 256*256
    bf16* wcat   = wvt + 256 * 256;          // 480*256
    bf16* woutt  = wcat + 480 * 256;         // 256*256
    bf16* w1t    = woutt + 256 * 256;        // 2048*256
    bf16* w2t    = w1t + 2048 * 256;         // 256*2048
    float* bcat  = (float*)(w2t + 256 * 2048); // 480 f32, ends ~182.6 MB
    (void)ws_size; (void)n_in; (void)in_sizes; (void)out_size;

    const int mt = (M + 127) / 128;  // 209

    // ---- fused weight prep (one launch) ----
    prep_kernel<<<1274, 256, 0, stream>>>(wv, wo, wa, wout, w1, w2, bo, ba,
                                          wvt, wcat, woutt, w1t, w2t, bcat);

    // ---- fused activation casts ----
    cast2_kernel<<<(M * C + 255) / 256, 256, 0, stream>>>(src, pos, src_b, q_b, M * C);

    // value = src @ wv + bv  (bf16)  [N=256 -> 64-wide tiles, 836 blocks]
    gemm_mfma64<false, true, false><<<dim3(4, mt), 256, 0, stream>>>(
        (const ushort_t*)src_b, (const ushort_t*)wvt, bv, nullptr, val_b, M, 256, 256);

    // og = q @ [wo|wa] + [bo|ba]  (f32, N=480)
    gemm_mfma<false, false, false><<<dim3(4, mt), 256, 0, stream>>>(
        (const ushort_t*)q_b, (const ushort_t*)wcat, bcat, nullptr, og, M, 480, 256);

    // deformable attention -> acc_b (bf16)
    msda_kernel_v3<<<(M + 7) / 8, 256, 0, stream>>>(
        og, refp, (const ushort_t*)val_b, acc_b, M, L);

    // y = acc @ wout + bout + src  (f32)  [N=256 -> 64-wide tiles]
    gemm_mfma64<false, false, true><<<dim3(4, mt), 256, 0, stream>>>(
        (const ushort_t*)acc_b, (const ushort_t*)woutt, bout, src, y, M, 256, 256);

    // x = LN1(y)
    ln_kernel<true><<<M, 256, 0, stream>>>(y, ln1g, ln1b, x_f, x_b);

    // h = relu(x @ w1 + b1)  (bf16)
    gemm_mfma<true, true, false><<<dim3(16, mt), 256, 0, stream>>>(
        (const ushort_t*)x_b, (const ushort_t*)w1t, b1, nullptr, h_b, M, FF, 256);

    // z = h @ w2 + b2 + x  (f32)  [N=256 -> 64-wide tiles]
    gemm_mfma64<false, false, true><<<dim3(4, mt), 256, 0, stream>>>(
        (const ushort_t*)h_b, (const ushort_t*)w2t, b2, x_f, z, M, 256, FF);

    // out = LN2(z)
    ln_kernel<false><<<M, 256, 0, stream>>>(z, ln2g, ln2b, (float*)d_out, nullptr);
}

// Round 9
// 435.616 us; speedup vs baseline: 4.4779x; 1.0317x over previous
//
#include <hip/hip_runtime.h>
#include <hip/hip_bf16.h>

typedef __hip_bfloat16 bf16;
typedef unsigned short ushort_t;
typedef __attribute__((ext_vector_type(8))) short bf16x8;
typedef __attribute__((ext_vector_type(16))) float f32x16;

__device__ __forceinline__ float us2f(unsigned short u) {
    unsigned int x = ((unsigned int)u) << 16;
    return __uint_as_float(x);
}

// async global->LDS, 16 B per lane. LDS dest = wave-uniform base + lane*16.
__device__ __forceinline__ void gl_lds16(const ushort_t* g, ushort_t* l) {
    __builtin_amdgcn_global_load_lds(
        (const __attribute__((address_space(1))) void*)g,
        (__attribute__((address_space(3))) void*)l, 16, 0, 0);
}

// ---------------------------------------------------------------------------
// Fused input cast: src_b = bf16(src), q_b = bf16(src + pos)
// ---------------------------------------------------------------------------
__global__ __launch_bounds__(256) void cast2_kernel(
    const float* __restrict__ src, const float* __restrict__ pos,
    bf16* __restrict__ src_b, bf16* __restrict__ q_b, int n)
{
    int i = blockIdx.x * 256 + threadIdx.x;
    if (i < n) {
        float s = src[i];
        src_b[i] = __float2bfloat16(s);
        q_b[i]   = __float2bfloat16(s + pos[i]);
    }
}

// ---------------------------------------------------------------------------
// Fused weight prep: all transpose-casts + bias concat in ONE launch.
// ---------------------------------------------------------------------------
__global__ __launch_bounds__(256) void prep_kernel(
    const float* __restrict__ wv, const float* __restrict__ wo,
    const float* __restrict__ wa, const float* __restrict__ wout,
    const float* __restrict__ w1, const float* __restrict__ w2,
    const float* __restrict__ bo, const float* __restrict__ ba,
    bf16* __restrict__ wvt, bf16* __restrict__ wcat, bf16* __restrict__ woutt,
    bf16* __restrict__ w1t, bf16* __restrict__ w2t, float* __restrict__ bcat)
{
    __shared__ float tile[32][33];
    const int b = blockIdx.x;
    const float* W; bf16* Wt; int K, N, tb;
    if (b < 64)        { W = wv;   Wt = wvt;            K = 256;  N = 256;  tb = b; }
    else if (b < 144)  { W = wo;   Wt = wcat;           K = 256;  N = 320;  tb = b - 64; }
    else if (b < 184)  { W = wa;   Wt = wcat + 320*256; K = 256;  N = 160;  tb = b - 144; }
    else if (b < 248)  { W = wout; Wt = woutt;          K = 256;  N = 256;  tb = b - 184; }
    else if (b < 760)  { W = w1;   Wt = w1t;            K = 256;  N = 2048; tb = b - 248; }
    else if (b < 1272) { W = w2;   Wt = w2t;            K = 2048; N = 256;  tb = b - 760; }
    else {
        int i = (b - 1272) * 256 + threadIdx.x;
        if (i < 320) bcat[i] = bo[i];
        else if (i < 480) bcat[i] = ba[i - 320];
        return;
    }
    const int ntn = N >> 5;
    const int nb = (tb % ntn) * 32, kb = (tb / ntn) * 32;
    const int tx = threadIdx.x & 31, ty = threadIdx.x >> 5;  // 32 x 8
    #pragma unroll
    for (int i = 0; i < 32; i += 8) {
        int k = kb + ty + i, n = nb + tx;
        tile[ty + i][tx] = (k < K && n < N) ? W[(size_t)k * N + n] : 0.f;
    }
    __syncthreads();
    #pragma unroll
    for (int i = 0; i < 32; i += 8) {
        int n = nb + ty + i, k = kb + tx;
        if (n < N && k < K)
            Wt[(size_t)n * K + k] = __float2bfloat16(tile[tx][ty + i]);
    }
}

// ---------------------------------------------------------------------------
// MFMA bf16 GEMM (128x128 tile): for large-N GEMMs (og N=480, FFN1 N=2048).
// ---------------------------------------------------------------------------
template<bool RELU, bool OUT_BF16, bool HAS_RESID>
__global__ __launch_bounds__(256, 4) void gemm_mfma(
    const ushort_t* __restrict__ A,    // [M][K] bf16
    const ushort_t* __restrict__ Bt,   // [N][K] bf16
    const float* __restrict__ bias,    // [N] f32
    const float* __restrict__ resid,   // [M][N] f32
    void* __restrict__ outv, int M, int N, int K)
{
    __shared__ ushort_t Asmem[128 * 32];
    __shared__ ushort_t Bsmem[128 * 32];
    const int tid = threadIdx.x;
    const int lane = tid & 63;
    const int wave = tid >> 6;
    const int l32 = lane & 31;
    const int hi  = lane >> 5;
    const int wm = wave >> 1, wn = wave & 1;
    const int m0 = blockIdx.y * 128;
    const int n0 = blockIdx.x * 128;

    const int srow = lane >> 2;
    const int sch  = (lane & 3) * 8;

    const ushort_t* aP[2]; const ushort_t* bP[2];
    ushort_t* aL[2]; ushort_t* bL[2];
    #pragma unroll
    for (int i = 0; i < 2; ++i) {
        const int rbase = wave * 32 + i * 16;
        int mA = m0 + rbase + srow; if (mA > M - 1) mA = M - 1;
        int nB = n0 + rbase + srow; if (nB > N - 1) nB = N - 1;
        aP[i] = A  + (size_t)mA * K + sch;
        bP[i] = Bt + (size_t)nB * K + sch;
        aL[i] = &Asmem[rbase * 32];
        bL[i] = &Bsmem[rbase * 32];
    }

    f32x16 acc[2][2] = {};

    for (int k0 = 0; k0 < K; k0 += 32) {
        #pragma unroll
        for (int i = 0; i < 2; ++i) {
            gl_lds16(aP[i], aL[i]);
            gl_lds16(bP[i], bL[i]);
            aP[i] += 32; bP[i] += 32;
        }
        __syncthreads();

        #pragma unroll
        for (int kw = 0; kw < 2; ++kw) {
            bf16x8 af[2], bfr[2];
            #pragma unroll
            for (int i = 0; i < 2; ++i) {
                const int rowA = wm * 64 + i * 32 + l32;
                af[i] = *reinterpret_cast<const bf16x8*>(
                    &Asmem[rowA * 32 + kw * 16 + hi * 8]);
                const int rowB = wn * 64 + i * 32 + l32;
                bfr[i] = *reinterpret_cast<const bf16x8*>(
                    &Bsmem[rowB * 32 + kw * 16 + hi * 8]);
            }
            #pragma unroll
            for (int i = 0; i < 2; ++i)
                #pragma unroll
                for (int j = 0; j < 2; ++j)
                    acc[i][j] = __builtin_amdgcn_mfma_f32_32x32x16_bf16(
                        af[i], bfr[j], acc[i][j], 0, 0, 0);
        }
        __syncthreads();
    }

    // epilogue: 32x32 C/D layout col = lane&31, row = (r&3) + 8*(r>>2) + 4*hi
    #pragma unroll
    for (int i = 0; i < 2; ++i) {
        const int mb = m0 + wm * 64 + i * 32 + hi * 4;
        #pragma unroll
        for (int j = 0; j < 2; ++j) {
            const int n = n0 + wn * 64 + j * 32 + l32;
            if (n >= N) continue;
            const float bval = bias[n];
            #pragma unroll
            for (int r = 0; r < 16; ++r) {
                const int m = mb + (r & 3) + (r >> 2) * 8;
                if (m >= M) continue;
                float v = acc[i][j][r] + bval;
                if (HAS_RESID) v += resid[(size_t)m * N + n];
                if (RELU) v = fmaxf(v, 0.f);
                if (OUT_BF16)
                    ((bf16*)outv)[(size_t)m * N + n] = __float2bfloat16(v);
                else
                    ((float*)outv)[(size_t)m * N + n] = v;
            }
        }
    }
}

// ---------------------------------------------------------------------------
// MFMA bf16 GEMM (64x128 tile, M-split): for N=256 GEMMs (value, wout, FFN2).
// vs R8's N-split: parallelism from M (A rows still read once per n-tile ->
// no FETCH inflation; R8 evidence: N-split 4x doubled HBM fetch to 232 MB).
// Grid dim3(2, ceil(M/64)) = 834 blocks = 2x R7's waves. 12 KB LDS, 32 AGPRs.
// ---------------------------------------------------------------------------
template<bool RELU, bool OUT_BF16, bool HAS_RESID>
__global__ __launch_bounds__(256, 4) void gemm_mfma_s(
    const ushort_t* __restrict__ A,    // [M][K] bf16
    const ushort_t* __restrict__ Bt,   // [N][K] bf16
    const float* __restrict__ bias,    // [N] f32
    const float* __restrict__ resid,   // [M][N] f32
    void* __restrict__ outv, int M, int N, int K)
{
    __shared__ ushort_t Asmem[64 * 32];
    __shared__ ushort_t Bsmem[128 * 32];
    const int tid = threadIdx.x;
    const int lane = tid & 63;
    const int wave = tid >> 6;
    const int l32 = lane & 31;
    const int hi  = lane >> 5;
    const int wm = wave >> 1;          // 0..1 -> m-offset wm*32
    const int wn = wave & 1;           // 0..1 -> n-offset wn*64
    const int m0 = blockIdx.y * 64;
    const int n0 = blockIdx.x * 128;

    const int srow = lane >> 2;        // 0..15
    const int sch  = (lane & 3) * 8;

    // A: 64 rows = 4 staging ops -> wave w stages rows w*16..w*16+15 (1 op)
    int mA = m0 + wave * 16 + srow; if (mA > M - 1) mA = M - 1;
    const ushort_t* aP = A + (size_t)mA * K + sch;
    ushort_t* aL = &Asmem[(wave * 16) * 32];
    // B: 128 rows = 8 ops -> wave w stages rows w*32..w*32+31 (2 ops)
    const ushort_t* bP[2]; ushort_t* bL[2];
    #pragma unroll
    for (int i = 0; i < 2; ++i) {
        const int rbase = wave * 32 + i * 16;
        int nB = n0 + rbase + srow; if (nB > N - 1) nB = N - 1;
        bP[i] = Bt + (size_t)nB * K + sch;
        bL[i] = &Bsmem[rbase * 32];
    }

    f32x16 acc[2] = {};

    for (int k0 = 0; k0 < K; k0 += 32) {
        gl_lds16(aP, aL);       aP    += 32;
        gl_lds16(bP[0], bL[0]); bP[0] += 32;
        gl_lds16(bP[1], bL[1]); bP[1] += 32;
        __syncthreads();

        #pragma unroll
        for (int kw = 0; kw < 2; ++kw) {
            const bf16x8 af = *reinterpret_cast<const bf16x8*>(
                &Asmem[(wm * 32 + l32) * 32 + kw * 16 + hi * 8]);
            bf16x8 bfr[2];
            #pragma unroll
            for (int j = 0; j < 2; ++j) {
                const int rowB = wn * 64 + j * 32 + l32;
                bfr[j] = *reinterpret_cast<const bf16x8*>(
                    &Bsmem[rowB * 32 + kw * 16 + hi * 8]);
            }
            #pragma unroll
            for (int j = 0; j < 2; ++j)
                acc[j] = __builtin_amdgcn_mfma_f32_32x32x16_bf16(
                    af, bfr[j], acc[j], 0, 0, 0);
        }
        __syncthreads();
    }

    // epilogue: wave owns rows m0+wm*32.., cols n0+wn*64 .. +64
    const int mb = m0 + wm * 32 + hi * 4;
    #pragma unroll
    for (int j = 0; j < 2; ++j) {
        const int n = n0 + wn * 64 + j * 32 + l32;
        if (n >= N) continue;
        const float bval = bias[n];
        #pragma unroll
        for (int r = 0; r < 16; ++r) {
            const int m = mb + (r & 3) + (r >> 2) * 8;
            if (m >= M) continue;
            float v = acc[j][r] + bval;
            if (HAS_RESID) v += resid[(size_t)m * N + n];
            if (RELU) v = fmaxf(v, 0.f);
            if (OUT_BF16)
                ((bf16*)outv)[(size_t)m * N + n] = __float2bfloat16(v);
            else
                ((float*)outv)[(size_t)m * N + n] = v;
        }
    }
}

// ---------------------------------------------------------------------------
// MS-deformable attention v3: phase-A tuple setup + phase-B pure gather-FMA.
// ---------------------------------------------------------------------------
__global__ __launch_bounds__(256) void msda_kernel_v3(
    const float* __restrict__ og,        // [M,480]: offs 0..319, logits 320..479
    const float* __restrict__ refp,      // [M,10]
    const ushort_t* __restrict__ value,  // [M,256] bf16 = (B,L,H,32)
    bf16* __restrict__ out,              // [M,256] bf16
    int M, int L)
{
    const int tid = threadIdx.x;
    const int qbase = blockIdx.x * 8;

    __shared__ float  s_attn[8][160];
    __shared__ int2   s_off[1280];
    __shared__ float4 s_w[1280];
    __shared__ int    s_Wl[5], s_St[5];

    if (tid < 5) {
        const int HW[5] = {100, 50, 25, 13, 7};
        const int st[5] = {0, 10000, 12500, 13125, 13294};
        s_Wl[tid] = HW[tid];
        s_St[tid] = st[tid];
    }

    for (int i = tid; i < 1280; i += 256) {
        int q = i / 160, j = i - q * 160;
        int qq = qbase + q;
        s_attn[q][j] = (qq < M) ? og[(size_t)qq * 480 + 320 + j] : 0.f;
    }
    __syncthreads();

    if (tid < 64) {
        float* a = &s_attn[tid >> 3][(tid & 7) * 20];
        float mx = -1e30f;
        #pragma unroll
        for (int i = 0; i < 20; ++i) mx = fmaxf(mx, a[i]);
        float ssum = 0.f;
        #pragma unroll
        for (int i = 0; i < 20; ++i) {
            float e = __expf(a[i] - mx);
            a[i] = e;
            ssum += e;
        }
        float inv = 1.f / ssum;
        #pragma unroll
        for (int i = 0; i < 20; ++i) a[i] *= inv;
    }
    __syncthreads();

    #pragma unroll
    for (int it = 0; it < 5; ++it) {
        const int t = tid + it * 256;
        const int q  = t / 160;
        const int r  = t - q * 160;
        const int l  = (r - (r / 20) * 20) >> 2;
        const int qq = qbase + q;

        int2 offp = {0, 0};
        float4 wp = {0.f, 0.f, 0.f, 0.f};
        if (qq < M) {
            const int Wi = s_Wl[l];
            const int s0 = s_St[l];
            const float Wf = (float)Wi;
            const float2 o2 = *reinterpret_cast<const float2*>(
                &og[(size_t)qq * 480 + r * 2]);
            const float2 rf = *reinterpret_cast<const float2*>(
                &refp[(size_t)qq * 10 + l * 2]);
            const float a = s_attn[q][r];

            const float px = fmaf(rf.x, Wf, -0.5f) + o2.x;
            const float py = fmaf(rf.y, Wf, -0.5f) + o2.y;
            const float x0f = floorf(px);
            const float y0f = floorf(py);
            const float lx = px - x0f;
            const float ly = py - y0f;
            const int x0 = (int)x0f;
            const int y0 = (int)y0f;

            const float wx0v = (x0 >= 0 && x0 < Wi) ? (1.f - lx) : 0.f;
            const float wx1v = (x0 + 1 >= 0 && x0 + 1 < Wi) ? lx : 0.f;
            const float wy0v = (y0 >= 0 && y0 < Wi) ? (1.f - ly) : 0.f;
            const float wy1v = (y0 + 1 >= 0 && y0 + 1 < Wi) ? ly : 0.f;

            const int c0 = min(max(x0, 0), Wi - 2);
            const int r0 = min(max(y0, 0), Wi - 2);
            const float swx0 = (x0 == c0 ? wx0v : 0.f) + (x0 + 1 == c0 ? wx1v : 0.f);
            const float swx1 = (x0 == c0 + 1 ? wx0v : 0.f) + (x0 + 1 == c0 + 1 ? wx1v : 0.f);
            const float swy0 = (y0 == r0 ? wy0v : 0.f) + (y0 + 1 == r0 ? wy1v : 0.f);
            const float swy1 = (y0 == r0 + 1 ? wy0v : 0.f) + (y0 + 1 == r0 + 1 ? wy1v : 0.f);

            offp.x = (s0 + r0 * Wi + c0) * 512;
            offp.y = offp.x + Wi * 512;
            wp.x = a * swx0 * swy0;
            wp.y = a * swx1 * swy0;
            wp.z = a * swx0 * swy1;
            wp.w = a * swx1 * swy1;
        }
        s_off[t] = offp;
        s_w[t] = wp;
    }
    __syncthreads();

    const int qi  = tid >> 5;
    const int g   = tid & 31;
    const int h   = g >> 2;
    const int sub = g & 3;
    const int bq = qbase + qi;
    if (bq >= M) return;
    const int b = bq / L;

    const char* vb = (const char*)value + (size_t)b * L * 512 + h * 64 + sub * 16;

    float acc[8] = {};
    const int tb = qi * 160 + h * 20;
    #pragma unroll 2
    for (int p = 0; p < 20; ++p) {
        const int2 off = s_off[tb + p];
        const float4 w = s_w[tb + p];
        const int4 u00 = *reinterpret_cast<const int4*>(vb + off.x);
        const int4 u10 = *reinterpret_cast<const int4*>(vb + off.x + 512);
        const int4 u01 = *reinterpret_cast<const int4*>(vb + off.y);
        const int4 u11 = *reinterpret_cast<const int4*>(vb + off.y + 512);
        #define ACC4(u, wt)                                                        \
            acc[0] = fmaf(wt, __uint_as_float((unsigned)(u).x << 16), acc[0]);      \
            acc[1] = fmaf(wt, __uint_as_float((unsigned)(u).x & 0xffff0000u), acc[1]); \
            acc[2] = fmaf(wt, __uint_as_float((unsigned)(u).y << 16), acc[2]);      \
            acc[3] = fmaf(wt, __uint_as_float((unsigned)(u).y & 0xffff0000u), acc[3]); \
            acc[4] = fmaf(wt, __uint_as_float((unsigned)(u).z << 16), acc[4]);      \
            acc[5] = fmaf(wt, __uint_as_float((unsigned)(u).z & 0xffff0000u), acc[5]); \
            acc[6] = fmaf(wt, __uint_as_float((unsigned)(u).w << 16), acc[6]);      \
            acc[7] = fmaf(wt, __uint_as_float((unsigned)(u).w & 0xffff0000u), acc[7]);
        ACC4(u00, w.x)
        ACC4(u10, w.y)
        ACC4(u01, w.z)
        ACC4(u11, w.w)
        #undef ACC4
    }

    ushort_t o[8];
    #pragma unroll
    for (int i = 0; i < 8; ++i)
        o[i] = ((__hip_bfloat16_raw)__float2bfloat16(acc[i])).x;
    int4 pkt;
    pkt.x = (int)o[0] | ((int)o[1] << 16);
    pkt.y = (int)o[2] | ((int)o[3] << 16);
    pkt.z = (int)o[4] | ((int)o[5] << 16);
    pkt.w = (int)o[6] | ((int)o[7] << 16);
    *reinterpret_cast<int4*>((ushort_t*)out + (size_t)bq * 256 + h * 32 + sub * 8) = pkt;
}

// ---------------------------------------------------------------------------
template<bool DUAL>
__global__ __launch_bounds__(256) void ln_kernel(
    const float* __restrict__ y, const float* __restrict__ g,
    const float* __restrict__ bta, float* __restrict__ outf,
    bf16* __restrict__ outb)
{
    const int row = blockIdx.x;
    const int tid = threadIdx.x;
    float v = y[(size_t)row * 256 + tid];
    float s = v, ss = v * v;
    #pragma unroll
    for (int o = 32; o > 0; o >>= 1) {
        s += __shfl_down(s, o);
        ss += __shfl_down(ss, o);
    }
    __shared__ float red[8];
    const int wid = tid >> 6, lane = tid & 63;
    if (lane == 0) { red[wid] = s; red[4 + wid] = ss; }
    __syncthreads();
    const float S = red[0] + red[1] + red[2] + red[3];
    const float SS = red[4] + red[5] + red[6] + red[7];
    const float mean = S * (1.f / 256.f);
    const float var = SS * (1.f / 256.f) - mean * mean;
    const float rs = rsqrtf(var + 1e-5f);
    const float o = (v - mean) * rs * g[tid] + bta[tid];
    outf[(size_t)row * 256 + tid] = o;
    if (DUAL) outb[(size_t)row * 256 + tid] = __float2bfloat16(o);
}

// ---------------------------------------------------------------------------
extern "C" void kernel_launch(void* const* d_in, const int* in_sizes, int n_in,
                              void* d_out, int out_size, void* d_ws, size_t ws_size,
                              hipStream_t stream)
{
    const int B = 2, L = 13343, C = 256, FF = 2048;
    const int M = B * L;  // 26686

    const float* src  = (const float*)d_in[0];
    const float* pos  = (const float*)d_in[1];
    const float* refp = (const float*)d_in[2];
    const float* wv   = (const float*)d_in[3];
    const float* bv   = (const float*)d_in[4];
    const float* wo   = (const float*)d_in[5];
    const float* bo   = (const float*)d_in[6];
    const float* wa   = (const float*)d_in[7];
    const float* ba   = (const float*)d_in[8];
    const float* wout = (const float*)d_in[9];
    const float* bout = (const float*)d_in[10];
    const float* ln1g = (const float*)d_in[11];
    const float* ln1b = (const float*)d_in[12];
    const float* w1   = (const float*)d_in[13];
    const float* b1   = (const float*)d_in[14];
    const float* w2   = (const float*)d_in[15];
    const float* b2   = (const float*)d_in[16];
    const float* ln2g = (const float*)d_in[17];
    const float* ln2b = (const float*)d_in[18];

    char* ws = (char*)d_ws;
    const size_t MB = 1ull << 20;
    // ---- workspace overlay (peak ~184 MB) ----
    bf16*  src_b  = (bf16*)(ws + 0);         // 13.7 MB
    bf16*  q_b    = (bf16*)(ws + 14 * MB);   // 13.7
    bf16*  val_b  = (bf16*)(ws + 28 * MB);   // 13.7
    float* og     = (float*)(ws + 42 * MB);  // M*480 f32 = 51.2 -> ends 93.2
    bf16*  acc_b  = (bf16*)(ws + 95 * MB);   // 13.7 -> ends 108.7
    bf16*  h_b    = (bf16*)(ws + 0);         // M*2048 bf16 = 109.3 (overlays dead)
    float* y      = (float*)(ws + 110 * MB); // 27.3 (dead after LN1)
    float* z      = (float*)(ws + 110 * MB); // overlays y
    bf16*  x_b    = (bf16*)(ws + 138 * MB);  // 13.7
    float* x_f    = (float*)(ws + 152 * MB); // 27.3 -> ends 179.3
    bf16* wvt    = (bf16*)(ws + 180 * MB);   // 256*256
    bf16* wcat   = wvt + 256 * 256;          // 480*256
    bf16* woutt  = wcat + 480 * 256;         // 256*256
    bf16* w1t    = woutt + 256 * 256;        // 2048*256
    bf16* w2t    = w1t + 2048 * 256;         // 256*2048
    float* bcat  = (float*)(w2t + 256 * 2048); // 480 f32, ends ~182.6 MB
    (void)ws_size; (void)n_in; (void)in_sizes; (void)out_size;

    const int mt   = (M + 127) / 128;  // 209
    const int mt64 = (M + 63) / 64;    // 417

    // ---- fused weight prep (one launch) ----
    prep_kernel<<<1274, 256, 0, stream>>>(wv, wo, wa, wout, w1, w2, bo, ba,
                                          wvt, wcat, woutt, w1t, w2t, bcat);

    // ---- fused activation casts ----
    cast2_kernel<<<(M * C + 255) / 256, 256, 0, stream>>>(src, pos, src_b, q_b, M * C);

    // value = src @ wv + bv  (bf16)  [N=256 -> 64x128 M-split tiles]
    gemm_mfma_s<false, true, false><<<dim3(2, mt64), 256, 0, stream>>>(
        (const ushort_t*)src_b, (const ushort_t*)wvt, bv, nullptr, val_b, M, 256, 256);

    // og = q @ [wo|wa] + [bo|ba]  (f32, N=480)
    gemm_mfma<false, false, false><<<dim3(4, mt), 256, 0, stream>>>(
        (const ushort_t*)q_b, (const ushort_t*)wcat, bcat, nullptr, og, M, 480, 256);

    // deformable attention -> acc_b (bf16)
    msda_kernel_v3<<<(M + 7) / 8, 256, 0, stream>>>(
        og, refp, (const ushort_t*)val_b, acc_b, M, L);

    // y = acc @ wout + bout + src  (f32)  [64x128 tiles]
    gemm_mfma_s<false, false, true><<<dim3(2, mt64), 256, 0, stream>>>(
        (const ushort_t*)acc_b, (const ushort_t*)woutt, bout, src, y, M, 256, 256);

    // x = LN1(y)
    ln_kernel<true><<<M, 256, 0, stream>>>(y, ln1g, ln1b, x_f, x_b);

    // h = relu(x @ w1 + b1)  (bf16)
    gemm_mfma<true, true, false><<<dim3(16, mt), 256, 0, stream>>>(
        (const ushort_t*)x_b, (const ushort_t*)w1t, b1, nullptr, h_b, M, FF, 256);

    // z = h @ w2 + b2 + x  (f32)  [64x128 tiles, K=2048]
    gemm_mfma_s<false, false, true><<<dim3(2, mt64), 256, 0, stream>>>(
        (const ushort_t*)h_b, (const ushort_t*)w2t, b2, x_f, z, M, 256, FF);

    // out = LN2(z)
    ln_kernel<false><<<M, 256, 0, stream>>>(z, ln2g, ln2b, (float*)d_out, nullptr);
}